// Round 13
// baseline (574.000 us; speedup 1.0000x reference)
//
#include <hip/hip_runtime.h>
#include <hip/hip_bf16.h>
#include <cstdint>

// ---------------------------------------------------------------------------
// ImageEncoder: 4-layer transformer encoder, N=4 S=2048 D=512 H=8 HD=64 F=200.
// bf16 residual stream + bf16 MFMA.
// R13 (604.9us): qkv V-epilogue packed 8B stores. R14/R15 (NEUTRAL): GEMM
// pipeline + swizzle, kept. R16 (580.7us): tmp stream bf16. R17/R18
// (REGRESS): attn q-split / LDS-side V-perm (bank conflicts). R19 (567.7us,
// WIN): bf16 residual stream, -200MB.
// R21: bake the PV kv-permutation INTO vtb's global layout (qkv V epilogue
// address map s' = (s&~31)|((s32&15)>>2)*8|((s32&16)?4:0); 4-runs stay
// 4-runs -> packed 8B store preserved; within-sector -> WRITE_SIZE same).
// attn: storeV becomes 2 contiguous b128 (repack gone), PV A-frag is ONE
// b128 read (slots 8q+j <-> kv {4q+j,16+4q+j} == old vlo/vhi assembly).
// Removes per jt: 16 b64 reads, ~64 repack VALU, staging repack. Unlike R18
// there are NO scattered LDS stores (its failure mode).
// ---------------------------------------------------------------------------

typedef __bf16 bf16;
typedef __bf16 bf16x8 __attribute__((ext_vector_type(8)));
typedef __bf16 bf16x4 __attribute__((ext_vector_type(4)));
typedef float f32x4 __attribute__((ext_vector_type(4)));

#define MFMA16(a, b, c) __builtin_amdgcn_mfma_f32_16x16x32_bf16((a), (b), (c), 0, 0, 0)

static constexpr int NB   = 4;
static constexpr int SQ   = 2048;
static constexpr int DM   = 512;
static constexpr int NH   = 8;
static constexpr int HD   = 64;
static constexpr int NL   = 4;
static constexpr int FF   = 200;
static constexpr int FFP  = 256;
static constexpr int MTOK = NB * SQ; // 8192

__device__ __forceinline__ float fast_exp2(float x) {
#if __has_builtin(__builtin_amdgcn_exp2f)
    return __builtin_amdgcn_exp2f(x);
#else
    return exp2f(x);
#endif
}

// async global->LDS, 16 bytes per lane
__device__ __forceinline__ void gld16(bf16* l, const bf16* g) {
    __builtin_amdgcn_global_load_lds(
        (const __attribute__((address_space(1))) void*)g,
        (__attribute__((address_space(3))) void*)l, 16, 0, 0);
}

__device__ __forceinline__ void drain_and_barrier() {
    asm volatile("s_waitcnt vmcnt(0) lgkmcnt(0)" ::: "memory");
    __builtin_amdgcn_s_barrier();
}

// ---------------------------------------------------------------------------
// Weight convert + transpose:  src fp32 [K, Nsrc]  ->  dst bf16 [Npad, Kpad]
// ---------------------------------------------------------------------------
__global__ __launch_bounds__(256) void convw_kernel(
    const float* __restrict__ Wq, const float* __restrict__ Wk,
    const float* __restrict__ Wv, const float* __restrict__ Wo,
    const float* __restrict__ W1, const float* __restrict__ W2,
    bf16* __restrict__ wqkvt, bf16* __restrict__ wot,
    bf16* __restrict__ w1t, bf16* __restrict__ w2t)
{
    __shared__ float tile[32][33];
    const int z = blockIdx.z, l = z / 6, which = z % 6;
    const float* src; bf16* dst; int K, Nsrc, Npad, Kpad;
    switch (which) {
        case 0: src = Wq + (size_t)l*DM*DM; dst = wqkvt + (size_t)(l*3+0)*DM*DM; K=DM; Nsrc=DM; Npad=DM; Kpad=DM; break;
        case 1: src = Wk + (size_t)l*DM*DM; dst = wqkvt + (size_t)(l*3+1)*DM*DM; K=DM; Nsrc=DM; Npad=DM; Kpad=DM; break;
        case 2: src = Wv + (size_t)l*DM*DM; dst = wqkvt + (size_t)(l*3+2)*DM*DM; K=DM; Nsrc=DM; Npad=DM; Kpad=DM; break;
        case 3: src = Wo + (size_t)l*DM*DM; dst = wot   + (size_t)l*DM*DM;       K=DM; Nsrc=DM; Npad=DM; Kpad=DM; break;
        case 4: src = W1 + (size_t)l*DM*FF; dst = w1t   + (size_t)l*FFP*DM;      K=DM; Nsrc=FF; Npad=FFP; Kpad=DM; break;
        default:src = W2 + (size_t)l*FF*DM; dst = w2t   + (size_t)l*DM*FFP;      K=FF; Nsrc=DM; Npad=DM; Kpad=FFP; break;
    }
    const int k0 = blockIdx.x * 32, n0 = blockIdx.y * 32;
    if (k0 >= Kpad || n0 >= Npad) return;
    const int tr = threadIdx.x >> 3, tc = (threadIdx.x & 7) * 4;
    for (int c = 0; c < 4; c++) {
        int sr = k0 + tr, sc = n0 + tc + c;
        tile[tr][tc + c] = (sr < K && sc < Nsrc) ? src[(size_t)sr * Nsrc + sc] : 0.f;
    }
    __syncthreads();
    const int dr = n0 + tr;
    if (dr < Npad) {
        for (int c = 0; c < 4; c++) {
            int dc = k0 + tc + c;
            if (dc < Kpad) dst[(size_t)dr * Kpad + dc] = (bf16)tile[tc + c][tr];
        }
    }
}

// ---------------------------------------------------------------------------
// Positional encoding add + cast (bf16 out only)
// ---------------------------------------------------------------------------
__global__ __launch_bounds__(256) void posenc_kernel(
    const float* __restrict__ f, bf16* __restrict__ xb)
{
    const int t = blockIdx.x * 256 + threadIdx.x;
    const int d2 = t & 255, row = t >> 8, s = row & (SQ - 1);
    const float kfac = -0.03597789207803197f;           // -2*ln(10000)/512
    float dv = __expf((float)d2 * kfac);
    float ang = (float)s * dv;
    float pe0 = sinf(ang), pe1 = cosf(ang);
    const size_t base = (size_t)row * DM + d2 * 2;
    float2 fv = *(const float2*)(f + base);
    float o0 = fv.x + pe0, o1 = fv.y + pe1;
    union { bf16 h[2]; unsigned int u; } pk;
    pk.h[0] = (bf16)o0; pk.h[1] = (bf16)o1;
    *(unsigned int*)(xb + base) = pk.u;
}

// ---------------------------------------------------------------------------
// R14+R15 GEMM core: 128x128 tile, BK=32, 4 waves; 3-buffer counted-vmcnt
// pipeline + XOR chunk-swizzled LDS (2-way max on fragment reads).
// ---------------------------------------------------------------------------
__device__ __forceinline__ void gemm128_core(
    const bf16* __restrict__ A, const bf16* __restrict__ Wt, int K,
    int m0, int n0, bf16* As, bf16* Bs, f32x4 (&acc)[4][4])
{
    const int tid = threadIdx.x;
    const int w = tid >> 6, lane = tid & 63;
    const int l15 = lane & 15, quad = lane >> 4;
    const int srow = w * 16 + (lane >> 2);
    // source pre-swizzle: chunk c of row r lands at physical chunk c^((r>>1)&3)
    const int scol = (((lane & 3) ^ ((lane >> 3) & 3))) * 8;
    const bf16* Ag = A  + (size_t)(m0 + srow) * K + scol;
    const bf16* Bg = Wt + (size_t)(n0 + srow) * K + scol;
    const int wm = (w >> 1) * 64, wn = (w & 1) * 64;

    auto stage = [&](int buf, int k0) {
        bf16* AsW = As + buf * 4096 + w * 512;
        bf16* BsW = Bs + buf * 4096 + w * 512;
        gld16(AsW,        Ag + k0);
        gld16(AsW + 2048, Ag + (size_t)64 * K + k0);
        gld16(BsW,        Bg + k0);
        gld16(BsW + 2048, Bg + (size_t)64 * K + k0);
    };

    const int nsteps = K >> 5;
    stage(0, 0);
    stage(1, 32);

    const int cx = (quad ^ ((l15 >> 1) & 3)) * 8;   // swizzled read chunk
    int buf = 0;
    for (int t = 0; t < nsteps; ++t) {
        if (t + 1 < nsteps)
            asm volatile("s_waitcnt vmcnt(4)" ::: "memory");
        else
            asm volatile("s_waitcnt vmcnt(0)" ::: "memory");
        __builtin_amdgcn_s_barrier();
        if (t + 2 < nsteps) {
            int b2 = buf + 2; if (b2 >= 3) b2 -= 3;
            stage(b2, (t + 2) << 5);
        }
        const bf16* AsR = As + buf * 4096;
        const bf16* BsR = Bs + buf * 4096;
        bf16x8 af[4], bfr[4];
        #pragma unroll
        for (int i = 0; i < 4; i++)
            af[i] = *(const bf16x8*)&AsR[(wm + i * 16 + l15) * 32 + cx];
        #pragma unroll
        for (int j = 0; j < 4; j++)
            bfr[j] = *(const bf16x8*)&BsR[(wn + j * 16 + l15) * 32 + cx];
        #pragma unroll
        for (int i = 0; i < 4; i++)
            #pragma unroll
            for (int j = 0; j < 4; j++)
                acc[i][j] = MFMA16(af[i], bfr[j], acc[i][j]);
        buf = (buf == 2) ? 0 : buf + 1;
    }
}

// 128x64-tile GEMM (wave-tile 64x32), counted-vmcnt + swizzled LDS.
// modes: 0 fp32, 1 bf16, 2 bf16 relu
__global__ __launch_bounds__(256, 4) void gemm64_kernel(
    const bf16* __restrict__ A, const bf16* __restrict__ Wt,
    const float* __restrict__ bias, int nbias,
    float* __restrict__ outf, bf16* __restrict__ outb,
    int K, int Nc, int mode)
{
    __shared__ alignas(16) bf16 As[3 * 128 * 32];
    __shared__ alignas(16) bf16 Bs[3 * 64 * 32];
    const int m0 = blockIdx.x * 128, n0 = blockIdx.y * 64;
    const int tid = threadIdx.x;
    const int w = tid >> 6, lane = tid & 63;
    const int l15 = lane & 15, quad = lane >> 4;
    const int srow = w * 16 + (lane >> 2);
    const int scol = (((lane & 3) ^ ((lane >> 3) & 3))) * 8;
    const bf16* Ag = A  + (size_t)(m0 + srow) * K + scol;
    const bf16* Bg = Wt + (size_t)(n0 + srow) * K + scol;
    const int wm = (w >> 1) * 64, wn = (w & 1) * 32;
    f32x4 acc[4][2] = {};

    auto stage = [&](int buf, int k0) {
        bf16* AsW = As + buf * 4096 + w * 512;
        bf16* BsW = Bs + buf * 2048 + w * 512;
        gld16(AsW,        Ag + k0);
        gld16(AsW + 2048, Ag + (size_t)64 * K + k0);
        gld16(BsW,        Bg + k0);
    };

    const int nsteps = K >> 5;
    stage(0, 0);
    stage(1, 32);

    const int cx = (quad ^ ((l15 >> 1) & 3)) * 8;
    int buf = 0;
    for (int t = 0; t < nsteps; ++t) {
        if (t + 1 < nsteps)
            asm volatile("s_waitcnt vmcnt(3)" ::: "memory");
        else
            asm volatile("s_waitcnt vmcnt(0)" ::: "memory");
        __builtin_amdgcn_s_barrier();
        if (t + 2 < nsteps) {
            int b2 = buf + 2; if (b2 >= 3) b2 -= 3;
            stage(b2, (t + 2) << 5);
        }
        const bf16* AsR = As + buf * 4096;
        const bf16* BsR = Bs + buf * 2048;
        bf16x8 af[4], bfr[2];
        #pragma unroll
        for (int i = 0; i < 4; i++)
            af[i] = *(const bf16x8*)&AsR[(wm + i * 16 + l15) * 32 + cx];
        #pragma unroll
        for (int j = 0; j < 2; j++)
            bfr[j] = *(const bf16x8*)&BsR[(wn + j * 16 + l15) * 32 + cx];
        #pragma unroll
        for (int i = 0; i < 4; i++)
            #pragma unroll
            for (int j = 0; j < 2; j++)
                acc[i][j] = MFMA16(af[i], bfr[j], acc[i][j]);
        buf = (buf == 2) ? 0 : buf + 1;
    }

    #pragma unroll
    for (int j = 0; j < 2; j++) {
        const int col = n0 + wn + j * 16 + l15;
        const float bv = (col < nbias) ? bias[col] : 0.f;
        #pragma unroll
        for (int i = 0; i < 4; i++) {
            const int rbase = m0 + wm + i * 16 + quad * 4;
            #pragma unroll
            for (int r = 0; r < 4; r++) {
                float v = acc[i][j][r] + bv;
                const int row = rbase + r;
                const size_t idx = (size_t)row * Nc + col;
                if (mode == 0)      outf[idx] = v;
                else if (mode == 1) outb[idx] = (bf16)v;
                else                outb[idx] = (bf16)fmaxf(v, 0.f);
            }
        }
    }
}

// Wo GEMM with fused attn-combine: A = bf16((o0+o1)*rl[head]) staged through
// VGPRs. A ds_write address swizzled; B gld16 source swizzled; reads swizzled.
__global__ __launch_bounds__(256, 4) void gemm_wo_kernel(
    const bf16* __restrict__ o0, const bf16* __restrict__ o1,
    const float* __restrict__ lpart,
    const bf16* __restrict__ Wt, const float* __restrict__ bias,
    bf16* __restrict__ outb)
{
    __shared__ alignas(16) bf16 As[2 * 128 * 32];
    __shared__ alignas(16) bf16 Bs[2 * 64 * 32];
    const int m0 = blockIdx.x * 128, n0 = blockIdx.y * 64;
    const int tid = threadIdx.x;
    const int w = tid >> 6, lane = tid & 63;
    const int l15 = lane & 15, quad = lane >> 4;
    const int srow = w * 16 + (lane >> 2);
    const int scol  = (lane & 3) * 8;                                  // linear (A reg loads)
    const int scolz = (((lane & 3) ^ ((lane >> 3) & 3))) * 8;          // swizzled (B gld16 src)
    const int row0 = m0 + srow, row1 = row0 + 64;
    const bf16* Bg = Wt + (size_t)(n0 + srow) * DM + scolz;
    const int wm = (w >> 1) * 64, wn = (w & 1) * 32;

    // per-head reciprocal softmax denominators for this thread's two A rows
    const int b0 = (((row0 >> 11) * 8) << 11) | (row0 & (SQ - 1));
    const int b1 = (((row1 >> 11) * 8) << 11) | (row1 & (SQ - 1));
    float rl0[8], rl1[8];
    #pragma unroll
    for (int h = 0; h < 8; h++) {
        rl0[h] = 1.f / (lpart[b0 + (h << 11)] + lpart[65536 + b0 + (h << 11)]);
        rl1[h] = 1.f / (lpart[b1 + (h << 11)] + lpart[65536 + b1 + (h << 11)]);
    }

    const bf16* A0g  = o0 + (size_t)row0 * DM + scol;
    const bf16* A0g2 = o0 + (size_t)row1 * DM + scol;
    const bf16* A1g  = o1 + (size_t)row0 * DM + scol;
    const bf16* A1g2 = o1 + (size_t)row1 * DM + scol;
    f32x4 acc[4][2] = {};

    // swizzled ds_write position: row (lane>>2), physical chunk (lane&3)^((lane>>3)&3)
    const int adst = (lane >> 2) * 32 + scolz;

    auto combineStore = [&](int buf, int h, bf16x8 a0, bf16x8 c0, bf16x8 a1, bf16x8 c1) {
        bf16x8 s0, s1;
        #pragma unroll
        for (int i = 0; i < 8; i++) {
            s0[i] = (bf16)(((float)a0[i] + (float)c0[i]) * rl0[h]);
            s1[i] = (bf16)(((float)a1[i] + (float)c1[i]) * rl1[h]);
        }
        bf16* d = As + buf * 4096 + w * 512 + adst;
        *(bf16x8*)d          = s0;
        *(bf16x8*)(d + 2048) = s1;
    };

    { // prologue: step 0
        bf16x8 a0 = *(const bf16x8*)(A0g);
        bf16x8 c0 = *(const bf16x8*)(A1g);
        bf16x8 a1 = *(const bf16x8*)(A0g2);
        bf16x8 c1 = *(const bf16x8*)(A1g2);
        gld16(Bs + w * 512, Bg);
        combineStore(0, 0, a0, c0, a1, c1);
        drain_and_barrier();
    }

    const int cx = (quad ^ ((l15 >> 1) & 3)) * 8;
    int buf = 0;
    for (int t = 0; t < 16; ++t) {
        const bool pre = (t + 1 < 16);
        bf16x8 na0, nc0, na1, nc1;
        if (pre) {
            const int k1 = (t + 1) * 32;
            na0 = *(const bf16x8*)(A0g  + k1);
            nc0 = *(const bf16x8*)(A1g  + k1);
            na1 = *(const bf16x8*)(A0g2 + k1);
            nc1 = *(const bf16x8*)(A1g2 + k1);
            gld16(Bs + (buf ^ 1) * 2048 + w * 512, Bg + k1);
        }

        const bf16* AsR = As + buf * 4096;
        const bf16* BsR = Bs + buf * 2048;
        bf16x8 af[4], bfr[2];
        #pragma unroll
        for (int i = 0; i < 4; i++)
            af[i] = *(const bf16x8*)&AsR[(wm + i * 16 + l15) * 32 + cx];
        #pragma unroll
        for (int j = 0; j < 2; j++)
            bfr[j] = *(const bf16x8*)&BsR[(wn + j * 16 + l15) * 32 + cx];
        #pragma unroll
        for (int i = 0; i < 4; i++)
            #pragma unroll
            for (int j = 0; j < 2; j++)
                acc[i][j] = MFMA16(af[i], bfr[j], acc[i][j]);

        if (pre) combineStore(buf ^ 1, (t + 1) >> 1, na0, nc0, na1, nc1);
        drain_and_barrier();
        buf ^= 1;
    }

    #pragma unroll
    for (int j = 0; j < 2; j++) {
        const int col = n0 + wn + j * 16 + l15;
        const float bv = bias[col];
        #pragma unroll
        for (int i = 0; i < 4; i++) {
            const int rbase = m0 + wm + i * 16 + quad * 4;
            #pragma unroll
            for (int r = 0; r < 4; r++)
                outb[(size_t)(rbase + r) * DM + col] = (bf16)(acc[i][j][r] + bv);
        }
    }
}

// fused QKV (128x128 core). Q gets (1/sqrt(HD))*log2(e) folded in;
// V written transposed to [n,h,hd,s'] with the PV kv-permutation baked into
// s' (R21): s' = (s&~31) | ((s32&15)>>2)*8 | ((s32&16)?4:0). 4-aligned runs
// stay 4-aligned -> packed 8B store preserved; within-sector -> no write amp.
__global__ __launch_bounds__(256, 3) void gemm128_qkv_kernel(
    const bf16* __restrict__ xb, const bf16* __restrict__ Wt,
    const float* __restrict__ bq, const float* __restrict__ bk,
    const float* __restrict__ bv,
    bf16* __restrict__ qb, bf16* __restrict__ kb, bf16* __restrict__ vtb)
{
    __shared__ alignas(16) bf16 As[3 * 128 * 32];
    __shared__ alignas(16) bf16 Bs[3 * 128 * 32];
    const int m0 = blockIdx.x * 128, n0 = blockIdx.y * 128;
    f32x4 acc[4][4] = {};
    gemm128_core(xb, Wt, DM, m0, n0, As, Bs, acc);

    const int lane = threadIdx.x & 63;
    const int l15 = lane & 15, quad = lane >> 4;
    const int w = threadIdx.x >> 6;
    const int wm = (w >> 1) * 64, wn = (w & 1) * 64;
    const int which = n0 >> 9;
    const float* bias = (which == 0) ? bq : (which == 1) ? bk : bv;
    // 0.125 = 1/sqrt(64); *1.44269504 so attn can use exp2 directly
    const float scale = (which == 0) ? 0.18033688f : 1.f;
    #pragma unroll
    for (int j = 0; j < 4; j++) {
        const int c = (n0 & 511) + wn + j * 16 + l15;
        const float bvv = bias[c];
        #pragma unroll
        for (int i = 0; i < 4; i++) {
            const int rbase = m0 + wm + i * 16 + quad * 4;
            if (which == 2) {
                // V: r=0..3 are s-contiguous -> one packed 8B store at the
                // permuted slot base (4-run maps to 4-run).
                union { bf16 h[4]; uint2 u2; } pk;
                #pragma unroll
                for (int r = 0; r < 4; r++)
                    pk.h[r] = (bf16)(acc[i][j][r] + bvv);
                const int n = rbase >> 11, s = rbase & (SQ - 1);
                const int s32 = s & 31;
                const int sp2 = (s & ~31) | (((s32 & 15) >> 2) << 3) | ((s32 & 16) ? 4 : 0);
                const int h = c >> 6, hd = c & 63;
                *(uint2*)&vtb[((size_t)(((n << 3) | h) << 6 | hd) << 11) | sp2] = pk.u2;
            } else {
                #pragma unroll
                for (int r = 0; r < 4; r++) {
                    float v = (acc[i][j][r] + bvv) * scale;
                    const int row = rbase + r;
                    if (which == 0) qb[(size_t)row * DM + c] = (bf16)v;
                    else            kb[(size_t)row * DM + c] = (bf16)v;
                }
            }
        }
    }
}

// ---------------------------------------------------------------------------
// Flash attention. Block: one (n,h,kvhalf), 256 q (4 waves x 64 q),
// 16 kv-tiles of 64. Grid 512.
// S^T = K·Q^T (16x16x32): lane holds q=l15, kv=quad*4+r; kv-permuted K=32 PV.
// R21: vtb is pre-permuted -> storeV is 2 contiguous b128 (no repack) and
// the PV A-operand is ONE b128 read at [d4*16+l15][sp*32+quad*8].
// lsum = P*ones via MFMA. Unnormalized O + lsum partials out.
// ---------------------------------------------------------------------------
__global__ __launch_bounds__(256, 2) void attn_kernel(
    const bf16* __restrict__ qb, const bf16* __restrict__ kb,
    const bf16* __restrict__ vtb,
    bf16* __restrict__ opart0, bf16* __restrict__ opart1,
    float* __restrict__ lpart)
{
    __shared__ alignas(16) bf16 Kt[2][64][72];
    __shared__ alignas(16) bf16 Vt[2 * 64 * 68];
    const int tid = threadIdx.x;
    const int w = tid >> 6, lane = tid & 63;
    const int l15 = lane & 15, quad = lane >> 4;
    const int id = blockIdx.x;          // id&7 fixed per (nh,kvhalf) -> XCD
    const int kvhalf = id & 1;
    const int nh = (id >> 1) & 31;
    const int qblk = id >> 6;           // [0,8)
    const int n = nh >> 3, h = nh & 7;
    const int q0 = qblk * 256 + w * 64;
    const int kvbase = kvhalf * (SQ / 2);
    const bf16* qbase = qb + (size_t)n * SQ * DM + h * HD;
    const bf16* kbase = kb + (size_t)n * SQ * DM + h * HD;
    const bf16* vbase = vtb + (size_t)nh * HD * SQ;

    // Q fragments (B-operand of S^T: n=q=l15, k=d=quad*8+j), 4 mi tiles
    bf16x8 qf[4][2];
    #pragma unroll
    for (int mi = 0; mi < 4; mi++)
        #pragma unroll
        for (int hh = 0; hh < 2; hh++)
            qf[mi][hh] = *(const bf16x8*)(qbase + (size_t)(q0 + mi*16 + l15) * DM + hh*32 + quad*8);

    bf16x8 ones8;
    #pragma unroll
    for (int i = 0; i < 8; i++) ones8[i] = (bf16)1.0f;

    f32x4 o[4][4] = {};
    f32x4 lacc[4] = {};

    // staging: thread covers (srow, seg..seg+16) of the 64x64 tile
    const int srow = tid >> 2, seg = (tid & 3) * 16;
    const bf16* krow = kbase + (size_t)(kvbase + srow) * DM + seg;  // K rows = kv
    const bf16* vrow = vbase + (size_t)srow * SQ + kvbase + seg;    // V rows = hd (pre-permuted s)

    { // prologue: stage tile 0 of this half
        bf16x8 k0 = *(const bf16x8*)(krow);
        bf16x8 k1 = *(const bf16x8*)(krow + 8);
        bf16x8 v0 = *(const bf16x8*)(vrow);
        bf16x8 v1 = *(const bf16x8*)(vrow + 8);
        *(bf16x8*)&Kt[0][srow][seg]     = k0;
        *(bf16x8*)&Kt[0][srow][seg + 8] = k1;
        bf16* vd = &Vt[srow * 68 + seg];
        *(bf16x8*)(vd)     = v0;
        *(bf16x8*)(vd + 8) = v1;
    }

    const int NT = SQ / 128;   // 16 tiles per half
    for (int jt = 0; jt < NT; jt++) {
        const int buf = jt & 1;
        __syncthreads();   // buf writes visible; prev iter's reads complete
        const bool pre = (jt + 1 < NT);
        bf16x8 k0, k1, v0, v1;
        if (pre) {         // next tile's global loads issued early
            const bf16* kp = krow + (size_t)(jt + 1) * 64 * DM;
            const bf16* vp = vrow + (jt + 1) * 64;
            k0 = *(const bf16x8*)(kp);
            k1 = *(const bf16x8*)(kp + 8);
            v0 = *(const bf16x8*)(vp);
            v1 = *(const bf16x8*)(vp + 8);
        }

        #pragma unroll
        for (int sp = 0; sp < 2; sp++) {
            // two 16-row kv chunks of this 32-span
            bf16x8 kfA0 = *(const bf16x8*)&Kt[buf][sp*32 + l15][quad*8];
            bf16x8 kfA1 = *(const bf16x8*)&Kt[buf][sp*32 + l15][32 + quad*8];
            bf16x8 kfB0 = *(const bf16x8*)&Kt[buf][sp*32 + 16 + l15][quad*8];
            bf16x8 kfB1 = *(const bf16x8*)&Kt[buf][sp*32 + 16 + l15][32 + quad*8];
            bf16x8 pf[4];
            #pragma unroll
            for (int mi = 0; mi < 4; mi++) {
                f32x4 sa = {}, sb = {};
                sa = MFMA16(kfA0, qf[mi][0], sa);
                sa = MFMA16(kfA1, qf[mi][1], sa);
                sb = MFMA16(kfB0, qf[mi][0], sb);
                sb = MFMA16(kfB1, qf[mi][1], sb);
                bf16x8 p;
                #pragma unroll
                for (int r = 0; r < 4; r++) {
                    p[r]     = (bf16)fast_exp2(sa[r]);
                    p[r + 4] = (bf16)fast_exp2(sb[r]);
                }
                pf[mi] = p;                      // permuted K=32 A-frag
                lacc[mi] = MFMA16(p, ones8, lacc[mi]);   // row sums
            }
            // O[q][hd] += P V  (K=32; V pre-permuted -> one b128 A-frag read)
            #pragma unroll
            for (int d4 = 0; d4 < 4; d4++) {
                bf16x8 vf = *(const bf16x8*)&Vt[(buf*64 + d4*16 + l15) * 68 + sp*32 + quad*8];
                #pragma unroll
                for (int mi = 0; mi < 4; mi++)
                    o[mi][d4] = MFMA16(pf[mi], vf, o[mi][d4]);
            }
        }

        if (pre) {
            *(bf16x8*)&Kt[buf^1][srow][seg]     = k0;
            *(bf16x8*)&Kt[buf^1][srow][seg + 8] = k1;
            bf16* vd = &Vt[((buf^1) * 64 + srow) * 68 + seg];
            *(bf16x8*)(vd)     = v0;
            *(bf16x8*)(vd + 8) = v1;
        }
    }

    // lacc[mi][r] = lsum for q = q0 + mi*16 + quad*4 + r (same in every l15
    // lane). One lane per quad writes 4 contiguous floats.
    if (l15 == 0) {
        const int base = (kvhalf << 16) + (nh << 11) + q0 + quad * 4;
        #pragma unroll
        for (int mi = 0; mi < 4; mi++) {
            float4 v4 = make_float4(lacc[mi][0], lacc[mi][1], lacc[mi][2], lacc[mi][3]);
            *(float4*)&lpart[base + mi * 16] = v4;
        }
    }

    // write unnormalized O partial (bf16)
    bf16* op = kvhalf ? opart1 : opart0;
    #pragma unroll
    for (int mi = 0; mi < 4; mi++) {
        #pragma unroll
        for (int d4 = 0; d4 < 4; d4++) {
            const int col = h * HD + d4 * 16 + l15;
            #pragma unroll
            for (int r = 0; r < 4; r++) {
                const int row = n * SQ + q0 + mi*16 + quad*4 + r;
                op[(size_t)row * DM + col] = (bf16)o[mi][d4][r];
            }
        }
    }
}

// ---------------------------------------------------------------------------
// Residual + LayerNorm: out = LN(res + add) * g + beta with bf16 res and
// add streams. Stats in fp32. Writes bf16 xb; optional fp32 out (final layer).
// ---------------------------------------------------------------------------
__global__ __launch_bounds__(256) void ln_kernel(
    const bf16* __restrict__ res, const bf16* __restrict__ add,
    const float* __restrict__ g, const float* __restrict__ beta,
    float* __restrict__ outf, bf16* __restrict__ outb)
{
    const int w = threadIdx.x >> 6, lane = threadIdx.x & 63;
    const size_t row = (size_t)blockIdx.x * 4 + w;
    const bf16* rp = res + row * DM;
    const bf16* ap = add + row * DM;
    float4 v[2];
    float s = 0.f, s2 = 0.f;
    #pragma unroll
    for (int i = 0; i < 2; i++) {
        const int idx = i * 64 + lane;
        bf16x4 a4 = *(const bf16x4*)(rp + idx * 4);
        bf16x4 c4 = *(const bf16x4*)(ap + idx * 4);
        float x0 = (float)a4[0] + (float)c4[0], x1 = (float)a4[1] + (float)c4[1];
        float x2 = (float)a4[2] + (float)c4[2], x3 = (float)a4[3] + (float)c4[3];
        v[i] = make_float4(x0, x1, x2, x3);
        s  += x0 + x1 + x2 + x3;
        s2 += x0*x0 + x1*x1 + x2*x2 + x3*x3;
    }
    for (int m = 1; m < 64; m <<= 1) {
        s  += __shfl_xor(s,  m, 64);
        s2 += __shfl_xor(s2, m, 64);
    }
    const float mean = s * (1.f / DM);
    const float var  = s2 * (1.f / DM) - mean * mean;
    const float rstd = rsqrtf(var + 1e-5f);
    #pragma unroll
    for (int i = 0; i < 2; i++) {
        const int idx = i * 64 + lane;
        float4 gw = ((const float4*)g)[idx], bw = ((const float4*)beta)[idx];
        float o0 = (v[i].x - mean) * rstd * gw.x + bw.x;
        float o1 = (v[i].y - mean) * rstd * gw.y + bw.y;
        float o2 = (v[i].z - mean) * rstd * gw.z + bw.z;
        float o3 = (v[i].w - mean) * rstd * gw.w + bw.w;
        union { bf16 h[4]; uint2 u; } pk;
        pk.h[0] = (bf16)o0; pk.h[1] = (bf16)o1; pk.h[2] = (bf16)o2; pk.h[3] = (bf16)o3;
        *(uint2*)(outb + row * DM + idx * 4) = pk.u;
        if (outf)
            ((float4*)(outf + row * DM))[idx] = make_float4(o0, o1, o2, o3);
    }
}

// ---------------------------------------------------------------------------
extern "C" void kernel_launch(void* const* d_in, const int* in_sizes, int n_in,
                              void* d_out, int out_size, void* d_ws, size_t ws_size,
                              hipStream_t stream)
{
    const float* features = (const float*)d_in[0];
    const float* Wq  = (const float*)d_in[1];
    const float* bq  = (const float*)d_in[2];
    const float* Wk  = (const float*)d_in[3];
    const float* bk  = (const float*)d_in[4];
    const float* Wv  = (const float*)d_in[5];
    const float* bv  = (const float*)d_in[6];
    const float* Wo  = (const float*)d_in[7];
    const float* bo  = (const float*)d_in[8];
    const float* W1  = (const float*)d_in[9];
    const float* b1  = (const float*)d_in[10];
    const float* W2  = (const float*)d_in[11];
    const float* b2  = (const float*)d_in[12];
    const float* ln1w = (const float*)d_in[13];
    const float* ln1b = (const float*)d_in[14];
    const float* ln2w = (const float*)d_in[15];
    const float* ln2b = (const float*)d_in[16];
    float* outp = (float*)d_out;

    char* p = (char*)d_ws;
    size_t off = 0;
    auto alloc = [&](size_t bytes) { void* r = p + off; off = (off + bytes + 255) & ~(size_t)255; return r; };
    const size_t tokD = (size_t)MTOK * DM;
    bf16* tmpb   = (bf16*)alloc(tokD * 2);
    bf16* xb     = (bf16*)alloc(tokD * 2);
    bf16* qb     = (bf16*)alloc(tokD * 2);
    bf16* kb     = (bf16*)alloc(tokD * 2);
    bf16* vtb    = (bf16*)alloc(tokD * 2);
    bf16* opart0 = (bf16*)alloc(tokD * 2);
    bf16* opart1 = (bf16*)alloc(tokD * 2);
    float* lpart = (float*)alloc(2 * 65536 * 4);
    bf16* ffh    = (bf16*)alloc((size_t)MTOK * FFP * 2);
    bf16* wqkvt  = (bf16*)alloc((size_t)NL * 3 * DM * DM * 2);
    bf16* wot    = (bf16*)alloc((size_t)NL * DM * DM * 2);
    bf16* w1t    = (bf16*)alloc((size_t)NL * FFP * DM * 2);
    bf16* w2t    = (bf16*)alloc((size_t)NL * DM * FFP * 2);
    (void)ws_size; (void)in_sizes; (void)n_in; (void)out_size;

    convw_kernel<<<dim3(16, 16, NL * 6), 256, 0, stream>>>(
        Wq, Wk, Wv, Wo, W1, W2, wqkvt, wot, w1t, w2t);

    posenc_kernel<<<MTOK, 256, 0, stream>>>(features, xb);

    for (int l = 0; l < NL; l++) {
        const bf16* wqkvt_l = wqkvt + (size_t)l * 3 * DM * DM;
        gemm128_qkv_kernel<<<dim3(MTOK / 128, 1536 / 128), 256, 0, stream>>>(
            xb, wqkvt_l, bq + l*DM, bk + l*DM, bv + l*DM, qb, kb, vtb);
        attn_kernel<<<512, 256, 0, stream>>>(qb, kb, vtb, opart0, opart1, lpart);
        // tmpb = combine(o0,o1,lpart) @ Wo + bo   (combine fused into staging)
        gemm_wo_kernel<<<dim3(MTOK / 128, DM / 64), 256, 0, stream>>>(
            opart0, opart1, lpart, wot + (size_t)l*DM*DM, bo + l*DM, tmpb);
        // xb <- LN(xb + tmpb)   (in-place residual stream, bf16)
        ln_kernel<<<MTOK / 4, 256, 0, stream>>>(xb, tmpb, ln1w + l*DM, ln1b + l*DM, nullptr, xb);
        gemm64_kernel<<<dim3(MTOK / 128, FFP / 64), 256, 0, stream>>>(
            xb, w1t + (size_t)l*FFP*DM, b1 + l*FF, FF, nullptr, ffh, DM, FFP, 2);
        gemm64_kernel<<<dim3(MTOK / 128, DM / 64), 256, 0, stream>>>(
            ffh, w2t + (size_t)l*DM*FFP, b2 + l*DM, DM, nullptr, tmpb, FFP, DM, 1);
        float* outdst = (l == NL - 1) ? outp : nullptr;
        ln_kernel<<<MTOK / 4, 256, 0, stream>>>(xb, tmpb, ln2w + l*DM, ln2b + l*DM, outdst, xb);
    }
}

// Round 14
// 566.410 us; speedup vs baseline: 1.0134x; 1.0134x over previous
//
#include <hip/hip_runtime.h>
#include <hip/hip_bf16.h>
#include <cstdint>

// ---------------------------------------------------------------------------
// ImageEncoder: 4-layer transformer encoder, N=4 S=2048 D=512 H=8 HD=64 F=200.
// bf16 residual stream + bf16 MFMA.
// WIN ledger (traffic cuts, 3/3 matched): R13 packed V stores (604.9),
// R16 tmp stream bf16 (580.7), R19 bf16 residual stream (567.7).
// NEUTRAL/REGRESS ledger (compute-internal, 0/5): R14 counted-vmcnt pipeline
// (kept, harmless), R15 LDS swizzle (kept), R17 attn q-split (reverted),
// R18 LDS-side V-perm (reverted), R21 global-side V-perm b128 PV read
// (574.0 — overlapping 4-bank spans at 136B row stride serialize worse than
// two b64; reverted).
// R22: exact revert to the R19 best (567.7us). attn = round-5 form.
// ---------------------------------------------------------------------------

typedef __bf16 bf16;
typedef __bf16 bf16x8 __attribute__((ext_vector_type(8)));
typedef __bf16 bf16x4 __attribute__((ext_vector_type(4)));
typedef float f32x4 __attribute__((ext_vector_type(4)));

#define MFMA16(a, b, c) __builtin_amdgcn_mfma_f32_16x16x32_bf16((a), (b), (c), 0, 0, 0)

static constexpr int NB   = 4;
static constexpr int SQ   = 2048;
static constexpr int DM   = 512;
static constexpr int NH   = 8;
static constexpr int HD   = 64;
static constexpr int NL   = 4;
static constexpr int FF   = 200;
static constexpr int FFP  = 256;
static constexpr int MTOK = NB * SQ; // 8192

__device__ __forceinline__ float fast_exp2(float x) {
#if __has_builtin(__builtin_amdgcn_exp2f)
    return __builtin_amdgcn_exp2f(x);
#else
    return exp2f(x);
#endif
}

// async global->LDS, 16 bytes per lane
__device__ __forceinline__ void gld16(bf16* l, const bf16* g) {
    __builtin_amdgcn_global_load_lds(
        (const __attribute__((address_space(1))) void*)g,
        (__attribute__((address_space(3))) void*)l, 16, 0, 0);
}

__device__ __forceinline__ void drain_and_barrier() {
    asm volatile("s_waitcnt vmcnt(0) lgkmcnt(0)" ::: "memory");
    __builtin_amdgcn_s_barrier();
}

// ---------------------------------------------------------------------------
// Weight convert + transpose:  src fp32 [K, Nsrc]  ->  dst bf16 [Npad, Kpad]
// ---------------------------------------------------------------------------
__global__ __launch_bounds__(256) void convw_kernel(
    const float* __restrict__ Wq, const float* __restrict__ Wk,
    const float* __restrict__ Wv, const float* __restrict__ Wo,
    const float* __restrict__ W1, const float* __restrict__ W2,
    bf16* __restrict__ wqkvt, bf16* __restrict__ wot,
    bf16* __restrict__ w1t, bf16* __restrict__ w2t)
{
    __shared__ float tile[32][33];
    const int z = blockIdx.z, l = z / 6, which = z % 6;
    const float* src; bf16* dst; int K, Nsrc, Npad, Kpad;
    switch (which) {
        case 0: src = Wq + (size_t)l*DM*DM; dst = wqkvt + (size_t)(l*3+0)*DM*DM; K=DM; Nsrc=DM; Npad=DM; Kpad=DM; break;
        case 1: src = Wk + (size_t)l*DM*DM; dst = wqkvt + (size_t)(l*3+1)*DM*DM; K=DM; Nsrc=DM; Npad=DM; Kpad=DM; break;
        case 2: src = Wv + (size_t)l*DM*DM; dst = wqkvt + (size_t)(l*3+2)*DM*DM; K=DM; Nsrc=DM; Npad=DM; Kpad=DM; break;
        case 3: src = Wo + (size_t)l*DM*DM; dst = wot   + (size_t)l*DM*DM;       K=DM; Nsrc=DM; Npad=DM; Kpad=DM; break;
        case 4: src = W1 + (size_t)l*DM*FF; dst = w1t   + (size_t)l*FFP*DM;      K=DM; Nsrc=FF; Npad=FFP; Kpad=DM; break;
        default:src = W2 + (size_t)l*FF*DM; dst = w2t   + (size_t)l*DM*FFP;      K=FF; Nsrc=DM; Npad=DM; Kpad=FFP; break;
    }
    const int k0 = blockIdx.x * 32, n0 = blockIdx.y * 32;
    if (k0 >= Kpad || n0 >= Npad) return;
    const int tr = threadIdx.x >> 3, tc = (threadIdx.x & 7) * 4;
    for (int c = 0; c < 4; c++) {
        int sr = k0 + tr, sc = n0 + tc + c;
        tile[tr][tc + c] = (sr < K && sc < Nsrc) ? src[(size_t)sr * Nsrc + sc] : 0.f;
    }
    __syncthreads();
    const int dr = n0 + tr;
    if (dr < Npad) {
        for (int c = 0; c < 4; c++) {
            int dc = k0 + tc + c;
            if (dc < Kpad) dst[(size_t)dr * Kpad + dc] = (bf16)tile[tc + c][tr];
        }
    }
}

// ---------------------------------------------------------------------------
// Positional encoding add + cast (bf16 out only)
// ---------------------------------------------------------------------------
__global__ __launch_bounds__(256) void posenc_kernel(
    const float* __restrict__ f, bf16* __restrict__ xb)
{
    const int t = blockIdx.x * 256 + threadIdx.x;
    const int d2 = t & 255, row = t >> 8, s = row & (SQ - 1);
    const float kfac = -0.03597789207803197f;           // -2*ln(10000)/512
    float dv = __expf((float)d2 * kfac);
    float ang = (float)s * dv;
    float pe0 = sinf(ang), pe1 = cosf(ang);
    const size_t base = (size_t)row * DM + d2 * 2;
    float2 fv = *(const float2*)(f + base);
    float o0 = fv.x + pe0, o1 = fv.y + pe1;
    union { bf16 h[2]; unsigned int u; } pk;
    pk.h[0] = (bf16)o0; pk.h[1] = (bf16)o1;
    *(unsigned int*)(xb + base) = pk.u;
}

// ---------------------------------------------------------------------------
// GEMM core: 128x128 tile, BK=32, 4 waves; 3-buffer counted-vmcnt pipeline +
// XOR chunk-swizzled LDS (2-way max on fragment reads).
// ---------------------------------------------------------------------------
__device__ __forceinline__ void gemm128_core(
    const bf16* __restrict__ A, const bf16* __restrict__ Wt, int K,
    int m0, int n0, bf16* As, bf16* Bs, f32x4 (&acc)[4][4])
{
    const int tid = threadIdx.x;
    const int w = tid >> 6, lane = tid & 63;
    const int l15 = lane & 15, quad = lane >> 4;
    const int srow = w * 16 + (lane >> 2);
    // source pre-swizzle: chunk c of row r lands at physical chunk c^((r>>1)&3)
    const int scol = (((lane & 3) ^ ((lane >> 3) & 3))) * 8;
    const bf16* Ag = A  + (size_t)(m0 + srow) * K + scol;
    const bf16* Bg = Wt + (size_t)(n0 + srow) * K + scol;
    const int wm = (w >> 1) * 64, wn = (w & 1) * 64;

    auto stage = [&](int buf, int k0) {
        bf16* AsW = As + buf * 4096 + w * 512;
        bf16* BsW = Bs + buf * 4096 + w * 512;
        gld16(AsW,        Ag + k0);
        gld16(AsW + 2048, Ag + (size_t)64 * K + k0);
        gld16(BsW,        Bg + k0);
        gld16(BsW + 2048, Bg + (size_t)64 * K + k0);
    };

    const int nsteps = K >> 5;
    stage(0, 0);
    stage(1, 32);

    const int cx = (quad ^ ((l15 >> 1) & 3)) * 8;   // swizzled read chunk
    int buf = 0;
    for (int t = 0; t < nsteps; ++t) {
        if (t + 1 < nsteps)
            asm volatile("s_waitcnt vmcnt(4)" ::: "memory");
        else
            asm volatile("s_waitcnt vmcnt(0)" ::: "memory");
        __builtin_amdgcn_s_barrier();
        if (t + 2 < nsteps) {
            int b2 = buf + 2; if (b2 >= 3) b2 -= 3;
            stage(b2, (t + 2) << 5);
        }
        const bf16* AsR = As + buf * 4096;
        const bf16* BsR = Bs + buf * 4096;
        bf16x8 af[4], bfr[4];
        #pragma unroll
        for (int i = 0; i < 4; i++)
            af[i] = *(const bf16x8*)&AsR[(wm + i * 16 + l15) * 32 + cx];
        #pragma unroll
        for (int j = 0; j < 4; j++)
            bfr[j] = *(const bf16x8*)&BsR[(wn + j * 16 + l15) * 32 + cx];
        #pragma unroll
        for (int i = 0; i < 4; i++)
            #pragma unroll
            for (int j = 0; j < 4; j++)
                acc[i][j] = MFMA16(af[i], bfr[j], acc[i][j]);
        buf = (buf == 2) ? 0 : buf + 1;
    }
}

// 128x64-tile GEMM (wave-tile 64x32), counted-vmcnt + swizzled LDS.
// modes: 0 fp32, 1 bf16, 2 bf16 relu
__global__ __launch_bounds__(256, 4) void gemm64_kernel(
    const bf16* __restrict__ A, const bf16* __restrict__ Wt,
    const float* __restrict__ bias, int nbias,
    float* __restrict__ outf, bf16* __restrict__ outb,
    int K, int Nc, int mode)
{
    __shared__ alignas(16) bf16 As[3 * 128 * 32];
    __shared__ alignas(16) bf16 Bs[3 * 64 * 32];
    const int m0 = blockIdx.x * 128, n0 = blockIdx.y * 64;
    const int tid = threadIdx.x;
    const int w = tid >> 6, lane = tid & 63;
    const int l15 = lane & 15, quad = lane >> 4;
    const int srow = w * 16 + (lane >> 2);
    const int scol = (((lane & 3) ^ ((lane >> 3) & 3))) * 8;
    const bf16* Ag = A  + (size_t)(m0 + srow) * K + scol;
    const bf16* Bg = Wt + (size_t)(n0 + srow) * K + scol;
    const int wm = (w >> 1) * 64, wn = (w & 1) * 32;
    f32x4 acc[4][2] = {};

    auto stage = [&](int buf, int k0) {
        bf16* AsW = As + buf * 4096 + w * 512;
        bf16* BsW = Bs + buf * 2048 + w * 512;
        gld16(AsW,        Ag + k0);
        gld16(AsW + 2048, Ag + (size_t)64 * K + k0);
        gld16(BsW,        Bg + k0);
    };

    const int nsteps = K >> 5;
    stage(0, 0);
    stage(1, 32);

    const int cx = (quad ^ ((l15 >> 1) & 3)) * 8;
    int buf = 0;
    for (int t = 0; t < nsteps; ++t) {
        if (t + 1 < nsteps)
            asm volatile("s_waitcnt vmcnt(3)" ::: "memory");
        else
            asm volatile("s_waitcnt vmcnt(0)" ::: "memory");
        __builtin_amdgcn_s_barrier();
        if (t + 2 < nsteps) {
            int b2 = buf + 2; if (b2 >= 3) b2 -= 3;
            stage(b2, (t + 2) << 5);
        }
        const bf16* AsR = As + buf * 4096;
        const bf16* BsR = Bs + buf * 2048;
        bf16x8 af[4], bfr[2];
        #pragma unroll
        for (int i = 0; i < 4; i++)
            af[i] = *(const bf16x8*)&AsR[(wm + i * 16 + l15) * 32 + cx];
        #pragma unroll
        for (int j = 0; j < 2; j++)
            bfr[j] = *(const bf16x8*)&BsR[(wn + j * 16 + l15) * 32 + cx];
        #pragma unroll
        for (int i = 0; i < 4; i++)
            #pragma unroll
            for (int j = 0; j < 2; j++)
                acc[i][j] = MFMA16(af[i], bfr[j], acc[i][j]);
        buf = (buf == 2) ? 0 : buf + 1;
    }

    #pragma unroll
    for (int j = 0; j < 2; j++) {
        const int col = n0 + wn + j * 16 + l15;
        const float bv = (col < nbias) ? bias[col] : 0.f;
        #pragma unroll
        for (int i = 0; i < 4; i++) {
            const int rbase = m0 + wm + i * 16 + quad * 4;
            #pragma unroll
            for (int r = 0; r < 4; r++) {
                float v = acc[i][j][r] + bv;
                const int row = rbase + r;
                const size_t idx = (size_t)row * Nc + col;
                if (mode == 0)      outf[idx] = v;
                else if (mode == 1) outb[idx] = (bf16)v;
                else                outb[idx] = (bf16)fmaxf(v, 0.f);
            }
        }
    }
}

// Wo GEMM with fused attn-combine: A = bf16((o0+o1)*rl[head]) staged through
// VGPRs. A ds_write address swizzled; B gld16 source swizzled; reads swizzled.
__global__ __launch_bounds__(256, 4) void gemm_wo_kernel(
    const bf16* __restrict__ o0, const bf16* __restrict__ o1,
    const float* __restrict__ lpart,
    const bf16* __restrict__ Wt, const float* __restrict__ bias,
    bf16* __restrict__ outb)
{
    __shared__ alignas(16) bf16 As[2 * 128 * 32];
    __shared__ alignas(16) bf16 Bs[2 * 64 * 32];
    const int m0 = blockIdx.x * 128, n0 = blockIdx.y * 64;
    const int tid = threadIdx.x;
    const int w = tid >> 6, lane = tid & 63;
    const int l15 = lane & 15, quad = lane >> 4;
    const int srow = w * 16 + (lane >> 2);
    const int scol  = (lane & 3) * 8;                                  // linear (A reg loads)
    const int scolz = (((lane & 3) ^ ((lane >> 3) & 3))) * 8;          // swizzled (B gld16 src)
    const int row0 = m0 + srow, row1 = row0 + 64;
    const bf16* Bg = Wt + (size_t)(n0 + srow) * DM + scolz;
    const int wm = (w >> 1) * 64, wn = (w & 1) * 32;

    // per-head reciprocal softmax denominators for this thread's two A rows
    const int b0 = (((row0 >> 11) * 8) << 11) | (row0 & (SQ - 1));
    const int b1 = (((row1 >> 11) * 8) << 11) | (row1 & (SQ - 1));
    float rl0[8], rl1[8];
    #pragma unroll
    for (int h = 0; h < 8; h++) {
        rl0[h] = 1.f / (lpart[b0 + (h << 11)] + lpart[65536 + b0 + (h << 11)]);
        rl1[h] = 1.f / (lpart[b1 + (h << 11)] + lpart[65536 + b1 + (h << 11)]);
    }

    const bf16* A0g  = o0 + (size_t)row0 * DM + scol;
    const bf16* A0g2 = o0 + (size_t)row1 * DM + scol;
    const bf16* A1g  = o1 + (size_t)row0 * DM + scol;
    const bf16* A1g2 = o1 + (size_t)row1 * DM + scol;
    f32x4 acc[4][2] = {};

    // swizzled ds_write position: row (lane>>2), physical chunk (lane&3)^((lane>>3)&3)
    const int adst = (lane >> 2) * 32 + scolz;

    auto combineStore = [&](int buf, int h, bf16x8 a0, bf16x8 c0, bf16x8 a1, bf16x8 c1) {
        bf16x8 s0, s1;
        #pragma unroll
        for (int i = 0; i < 8; i++) {
            s0[i] = (bf16)(((float)a0[i] + (float)c0[i]) * rl0[h]);
            s1[i] = (bf16)(((float)a1[i] + (float)c1[i]) * rl1[h]);
        }
        bf16* d = As + buf * 4096 + w * 512 + adst;
        *(bf16x8*)d          = s0;
        *(bf16x8*)(d + 2048) = s1;
    };

    { // prologue: step 0
        bf16x8 a0 = *(const bf16x8*)(A0g);
        bf16x8 c0 = *(const bf16x8*)(A1g);
        bf16x8 a1 = *(const bf16x8*)(A0g2);
        bf16x8 c1 = *(const bf16x8*)(A1g2);
        gld16(Bs + w * 512, Bg);
        combineStore(0, 0, a0, c0, a1, c1);
        drain_and_barrier();
    }

    const int cx = (quad ^ ((l15 >> 1) & 3)) * 8;
    int buf = 0;
    for (int t = 0; t < 16; ++t) {
        const bool pre = (t + 1 < 16);
        bf16x8 na0, nc0, na1, nc1;
        if (pre) {
            const int k1 = (t + 1) * 32;
            na0 = *(const bf16x8*)(A0g  + k1);
            nc0 = *(const bf16x8*)(A1g  + k1);
            na1 = *(const bf16x8*)(A0g2 + k1);
            nc1 = *(const bf16x8*)(A1g2 + k1);
            gld16(Bs + (buf ^ 1) * 2048 + w * 512, Bg + k1);
        }

        const bf16* AsR = As + buf * 4096;
        const bf16* BsR = Bs + buf * 2048;
        bf16x8 af[4], bfr[2];
        #pragma unroll
        for (int i = 0; i < 4; i++)
            af[i] = *(const bf16x8*)&AsR[(wm + i * 16 + l15) * 32 + cx];
        #pragma unroll
        for (int j = 0; j < 2; j++)
            bfr[j] = *(const bf16x8*)&BsR[(wn + j * 16 + l15) * 32 + cx];
        #pragma unroll
        for (int i = 0; i < 4; i++)
            #pragma unroll
            for (int j = 0; j < 2; j++)
                acc[i][j] = MFMA16(af[i], bfr[j], acc[i][j]);

        if (pre) combineStore(buf ^ 1, (t + 1) >> 1, na0, nc0, na1, nc1);
        drain_and_barrier();
        buf ^= 1;
    }

    #pragma unroll
    for (int j = 0; j < 2; j++) {
        const int col = n0 + wn + j * 16 + l15;
        const float bv = bias[col];
        #pragma unroll
        for (int i = 0; i < 4; i++) {
            const int rbase = m0 + wm + i * 16 + quad * 4;
            #pragma unroll
            for (int r = 0; r < 4; r++)
                outb[(size_t)(rbase + r) * DM + col] = (bf16)(acc[i][j][r] + bv);
        }
    }
}

// fused QKV (128x128 core). Q gets (1/sqrt(HD))*log2(e) folded in;
// V written transposed to [n,h,hd,s] with packed 8B stores (R13).
__global__ __launch_bounds__(256, 3) void gemm128_qkv_kernel(
    const bf16* __restrict__ xb, const bf16* __restrict__ Wt,
    const float* __restrict__ bq, const float* __restrict__ bk,
    const float* __restrict__ bv,
    bf16* __restrict__ qb, bf16* __restrict__ kb, bf16* __restrict__ vtb)
{
    __shared__ alignas(16) bf16 As[3 * 128 * 32];
    __shared__ alignas(16) bf16 Bs[3 * 128 * 32];
    const int m0 = blockIdx.x * 128, n0 = blockIdx.y * 128;
    f32x4 acc[4][4] = {};
    gemm128_core(xb, Wt, DM, m0, n0, As, Bs, acc);

    const int lane = threadIdx.x & 63;
    const int l15 = lane & 15, quad = lane >> 4;
    const int w = threadIdx.x >> 6;
    const int wm = (w >> 1) * 64, wn = (w & 1) * 64;
    const int which = n0 >> 9;
    const float* bias = (which == 0) ? bq : (which == 1) ? bk : bv;
    // 0.125 = 1/sqrt(64); *1.44269504 so attn can use exp2 directly
    const float scale = (which == 0) ? 0.18033688f : 1.f;
    #pragma unroll
    for (int j = 0; j < 4; j++) {
        const int c = (n0 & 511) + wn + j * 16 + l15;
        const float bvv = bias[c];
        #pragma unroll
        for (int i = 0; i < 4; i++) {
            const int rbase = m0 + wm + i * 16 + quad * 4;
            if (which == 2) {
                // V: r=0..3 are s-contiguous in vtb -> one packed 8B store
                union { bf16 h[4]; uint2 u2; } pk;
                #pragma unroll
                for (int r = 0; r < 4; r++)
                    pk.h[r] = (bf16)(acc[i][j][r] + bvv);
                const int n = rbase >> 11, s = rbase & (SQ - 1);
                const int h = c >> 6, hd = c & 63;
                *(uint2*)&vtb[((size_t)(((n << 3) | h) << 6 | hd) << 11) | s] = pk.u2;
            } else {
                #pragma unroll
                for (int r = 0; r < 4; r++) {
                    float v = (acc[i][j][r] + bvv) * scale;
                    const int row = rbase + r;
                    if (which == 0) qb[(size_t)row * DM + c] = (bf16)v;
                    else            kb[(size_t)row * DM + c] = (bf16)v;
                }
            }
        }
    }
}

// ---------------------------------------------------------------------------
// Flash attention (round-5 best form). Block: one (n,h,kvhalf),
// 256 q (4 waves x 64 q), 16 kv-tiles of 64. Grid 512.
// S^T = K·Q^T (16x16x32): lane holds q=l15, kv=quad*4+r; kv-permuted K=32 PV;
// lsum = P*ones via MFMA. Unnormalized O + lsum partials out.
// ---------------------------------------------------------------------------
__global__ __launch_bounds__(256, 2) void attn_kernel(
    const bf16* __restrict__ qb, const bf16* __restrict__ kb,
    const bf16* __restrict__ vtb,
    bf16* __restrict__ opart0, bf16* __restrict__ opart1,
    float* __restrict__ lpart)
{
    __shared__ alignas(16) bf16 Kt[2][64][72];
    __shared__ alignas(16) bf16 Vt[2 * 64 * 68];
    const int tid = threadIdx.x;
    const int w = tid >> 6, lane = tid & 63;
    const int l15 = lane & 15, quad = lane >> 4;
    const int id = blockIdx.x;          // id&7 fixed per (nh,kvhalf) -> XCD
    const int kvhalf = id & 1;
    const int nh = (id >> 1) & 31;
    const int qblk = id >> 6;           // [0,8)
    const int n = nh >> 3, h = nh & 7;
    const int q0 = qblk * 256 + w * 64;
    const int kvbase = kvhalf * (SQ / 2);
    const bf16* qbase = qb + (size_t)n * SQ * DM + h * HD;
    const bf16* kbase = kb + (size_t)n * SQ * DM + h * HD;
    const bf16* vbase = vtb + (size_t)nh * HD * SQ;

    // Q fragments (B-operand of S^T: n=q=l15, k=d=quad*8+j), 4 mi tiles
    bf16x8 qf[4][2];
    #pragma unroll
    for (int mi = 0; mi < 4; mi++)
        #pragma unroll
        for (int hh = 0; hh < 2; hh++)
            qf[mi][hh] = *(const bf16x8*)(qbase + (size_t)(q0 + mi*16 + l15) * DM + hh*32 + quad*8);

    bf16x8 ones8;
    #pragma unroll
    for (int i = 0; i < 8; i++) ones8[i] = (bf16)1.0f;

    f32x4 o[4][4] = {};
    f32x4 lacc[4] = {};

    // staging: thread covers (srow, seg..seg+16) of the 64x64 tile
    const int srow = tid >> 2, seg = (tid & 3) * 16;
    const bf16* krow = kbase + (size_t)(kvbase + srow) * DM + seg;  // K rows = kv
    const bf16* vrow = vbase + (size_t)srow * SQ + kvbase + seg;    // V rows = hd

    auto storeV = [&](int buf, bf16x8 a, bf16x8 b) {
        bf16* d = &Vt[(buf * 64 + srow) * 68 + seg];
        bf16x4 p0, p1, p2, p3;
        #pragma unroll
        for (int i = 0; i < 4; i++) { p0[i]=a[i]; p1[i]=a[i+4]; p2[i]=b[i]; p3[i]=b[i+4]; }
        *(bf16x4*)(d)      = p0;
        *(bf16x4*)(d + 4)  = p1;
        *(bf16x4*)(d + 8)  = p2;
        *(bf16x4*)(d + 12) = p3;
    };

    { // prologue: stage tile 0 of this half
        bf16x8 k0 = *(const bf16x8*)(krow);
        bf16x8 k1 = *(const bf16x8*)(krow + 8);
        bf16x8 v0 = *(const bf16x8*)(vrow);
        bf16x8 v1 = *(const bf16x8*)(vrow + 8);
        *(bf16x8*)&Kt[0][srow][seg]     = k0;
        *(bf16x8*)&Kt[0][srow][seg + 8] = k1;
        storeV(0, v0, v1);
    }

    const int NT = SQ / 128;   // 16 tiles per half
    for (int jt = 0; jt < NT; jt++) {
        const int buf = jt & 1;
        __syncthreads();   // buf writes visible; prev iter's reads complete
        const bool pre = (jt + 1 < NT);
        bf16x8 k0, k1, v0, v1;
        if (pre) {         // next tile's global loads issued early
            const bf16* kp = krow + (size_t)(jt + 1) * 64 * DM;
            const bf16* vp = vrow + (jt + 1) * 64;
            k0 = *(const bf16x8*)(kp);
            k1 = *(const bf16x8*)(kp + 8);
            v0 = *(const bf16x8*)(vp);
            v1 = *(const bf16x8*)(vp + 8);
        }

        #pragma unroll
        for (int sp = 0; sp < 2; sp++) {
            // two 16-row kv chunks of this 32-span
            bf16x8 kfA0 = *(const bf16x8*)&Kt[buf][sp*32 + l15][quad*8];
            bf16x8 kfA1 = *(const bf16x8*)&Kt[buf][sp*32 + l15][32 + quad*8];
            bf16x8 kfB0 = *(const bf16x8*)&Kt[buf][sp*32 + 16 + l15][quad*8];
            bf16x8 kfB1 = *(const bf16x8*)&Kt[buf][sp*32 + 16 + l15][32 + quad*8];
            bf16x8 pf[4];
            #pragma unroll
            for (int mi = 0; mi < 4; mi++) {
                f32x4 sa = {}, sb = {};
                sa = MFMA16(kfA0, qf[mi][0], sa);
                sa = MFMA16(kfA1, qf[mi][1], sa);
                sb = MFMA16(kfB0, qf[mi][0], sb);
                sb = MFMA16(kfB1, qf[mi][1], sb);
                bf16x8 p;
                #pragma unroll
                for (int r = 0; r < 4; r++) {
                    p[r]     = (bf16)fast_exp2(sa[r]);
                    p[r + 4] = (bf16)fast_exp2(sb[r]);
                }
                pf[mi] = p;                      // permuted K=32 A-frag
                lacc[mi] = MFMA16(p, ones8, lacc[mi]);   // row sums
            }
            // O[q][hd] += P V  (K=32, kv-permuted; V rows follow pi)
            #pragma unroll
            for (int d4 = 0; d4 < 4; d4++) {
                const bf16* vp2 = &Vt[(buf*64 + d4*16 + l15) * 68 + sp*32 + quad*4];
                bf16x4 vlo = *(const bf16x4*)(vp2);
                bf16x4 vhi = *(const bf16x4*)(vp2 + 16);
                bf16x8 vf;
                #pragma unroll
                for (int i = 0; i < 4; i++) { vf[i] = vlo[i]; vf[i+4] = vhi[i]; }
                #pragma unroll
                for (int mi = 0; mi < 4; mi++)
                    o[mi][d4] = MFMA16(pf[mi], vf, o[mi][d4]);
            }
        }

        if (pre) {
            *(bf16x8*)&Kt[buf^1][srow][seg]     = k0;
            *(bf16x8*)&Kt[buf^1][srow][seg + 8] = k1;
            storeV(buf^1, v0, v1);
        }
    }

    // lacc[mi][r] = lsum for q = q0 + mi*16 + quad*4 + r (same in every l15
    // lane). One lane per quad writes 4 contiguous floats.
    if (l15 == 0) {
        const int base = (kvhalf << 16) + (nh << 11) + q0 + quad * 4;
        #pragma unroll
        for (int mi = 0; mi < 4; mi++) {
            float4 v4 = make_float4(lacc[mi][0], lacc[mi][1], lacc[mi][2], lacc[mi][3]);
            *(float4*)&lpart[base + mi * 16] = v4;
        }
    }

    // write unnormalized O partial (bf16)
    bf16* op = kvhalf ? opart1 : opart0;
    #pragma unroll
    for (int mi = 0; mi < 4; mi++) {
        #pragma unroll
        for (int d4 = 0; d4 < 4; d4++) {
            const int col = h * HD + d4 * 16 + l15;
            #pragma unroll
            for (int r = 0; r < 4; r++) {
                const int row = n * SQ + q0 + mi*16 + quad*4 + r;
                op[(size_t)row * DM + col] = (bf16)o[mi][d4][r];
            }
        }
    }
}

// ---------------------------------------------------------------------------
// Residual + LayerNorm: out = LN(res + add) * g + beta with bf16 res and
// add streams. Stats in fp32. Writes bf16 xb; optional fp32 out (final layer).
// ---------------------------------------------------------------------------
__global__ __launch_bounds__(256) void ln_kernel(
    const bf16* __restrict__ res, const bf16* __restrict__ add,
    const float* __restrict__ g, const float* __restrict__ beta,
    float* __restrict__ outf, bf16* __restrict__ outb)
{
    const int w = threadIdx.x >> 6, lane = threadIdx.x & 63;
    const size_t row = (size_t)blockIdx.x * 4 + w;
    const bf16* rp = res + row * DM;
    const bf16* ap = add + row * DM;
    float4 v[2];
    float s = 0.f, s2 = 0.f;
    #pragma unroll
    for (int i = 0; i < 2; i++) {
        const int idx = i * 64 + lane;
        bf16x4 a4 = *(const bf16x4*)(rp + idx * 4);
        bf16x4 c4 = *(const bf16x4*)(ap + idx * 4);
        float x0 = (float)a4[0] + (float)c4[0], x1 = (float)a4[1] + (float)c4[1];
        float x2 = (float)a4[2] + (float)c4[2], x3 = (float)a4[3] + (float)c4[3];
        v[i] = make_float4(x0, x1, x2, x3);
        s  += x0 + x1 + x2 + x3;
        s2 += x0*x0 + x1*x1 + x2*x2 + x3*x3;
    }
    for (int m = 1; m < 64; m <<= 1) {
        s  += __shfl_xor(s,  m, 64);
        s2 += __shfl_xor(s2, m, 64);
    }
    const float mean = s * (1.f / DM);
    const float var  = s2 * (1.f / DM) - mean * mean;
    const float rstd = rsqrtf(var + 1e-5f);
    #pragma unroll
    for (int i = 0; i < 2; i++) {
        const int idx = i * 64 + lane;
        float4 gw = ((const float4*)g)[idx], bw = ((const float4*)beta)[idx];
        float o0 = (v[i].x - mean) * rstd * gw.x + bw.x;
        float o1 = (v[i].y - mean) * rstd * gw.y + bw.y;
        float o2 = (v[i].z - mean) * rstd * gw.z + bw.z;
        float o3 = (v[i].w - mean) * rstd * gw.w + bw.w;
        union { bf16 h[4]; uint2 u; } pk;
        pk.h[0] = (bf16)o0; pk.h[1] = (bf16)o1; pk.h[2] = (bf16)o2; pk.h[3] = (bf16)o3;
        *(uint2*)(outb + row * DM + idx * 4) = pk.u;
        if (outf)
            ((float4*)(outf + row * DM))[idx] = make_float4(o0, o1, o2, o3);
    }
}

// ---------------------------------------------------------------------------
extern "C" void kernel_launch(void* const* d_in, const int* in_sizes, int n_in,
                              void* d_out, int out_size, void* d_ws, size_t ws_size,
                              hipStream_t stream)
{
    const float* features = (const float*)d_in[0];
    const float* Wq  = (const float*)d_in[1];
    const float* bq  = (const float*)d_in[2];
    const float* Wk  = (const float*)d_in[3];
    const float* bk  = (const float*)d_in[4];
    const float* Wv  = (const float*)d_in[5];
    const float* bv  = (const float*)d_in[6];
    const float* Wo  = (const float*)d_in[7];
    const float* bo  = (const float*)d_in[8];
    const float* W1  = (const float*)d_in[9];
    const float* b1  = (const float*)d_in[10];
    const float* W2  = (const float*)d_in[11];
    const float* b2  = (const float*)d_in[12];
    const float* ln1w = (const float*)d_in[13];
    const float* ln1b = (const float*)d_in[14];
    const float* ln2w = (const float*)d_in[15];
    const float* ln2b = (const float*)d_in[16];
    float* outp = (float*)d_out;

    char* p = (char*)d_ws;
    size_t off = 0;
    auto alloc = [&](size_t bytes) { void* r = p + off; off = (off + bytes + 255) & ~(size_t)255; return r; };
    const size_t tokD = (size_t)MTOK * DM;
    bf16* tmpb   = (bf16*)alloc(tokD * 2);
    bf16* xb     = (bf16*)alloc(tokD * 2);
    bf16* qb     = (bf16*)alloc(tokD * 2);
    bf16* kb     = (bf16*)alloc(tokD * 2);
    bf16* vtb    = (bf16*)alloc(tokD * 2);
    bf16* opart0 = (bf16*)alloc(tokD * 2);
    bf16* opart1 = (bf16*)alloc(tokD * 2);
    float* lpart = (float*)alloc(2 * 65536 * 4);
    bf16* ffh    = (bf16*)alloc((size_t)MTOK * FFP * 2);
    bf16* wqkvt  = (bf16*)alloc((size_t)NL * 3 * DM * DM * 2);
    bf16* wot    = (bf16*)alloc((size_t)NL * DM * DM * 2);
    bf16* w1t    = (bf16*)alloc((size_t)NL * FFP * DM * 2);
    bf16* w2t    = (bf16*)alloc((size_t)NL * DM * FFP * 2);
    (void)ws_size; (void)in_sizes; (void)n_in; (void)out_size;

    convw_kernel<<<dim3(16, 16, NL * 6), 256, 0, stream>>>(
        Wq, Wk, Wv, Wo, W1, W2, wqkvt, wot, w1t, w2t);

    posenc_kernel<<<MTOK, 256, 0, stream>>>(features, xb);

    for (int l = 0; l < NL; l++) {
        const bf16* wqkvt_l = wqkvt + (size_t)l * 3 * DM * DM;
        gemm128_qkv_kernel<<<dim3(MTOK / 128, 1536 / 128), 256, 0, stream>>>(
            xb, wqkvt_l, bq + l*DM, bk + l*DM, bv + l*DM, qb, kb, vtb);
        attn_kernel<<<512, 256, 0, stream>>>(qb, kb, vtb, opart0, opart1, lpart);
        // tmpb = combine(o0,o1,lpart) @ Wo + bo   (combine fused into staging)
        gemm_wo_kernel<<<dim3(MTOK / 128, DM / 64), 256, 0, stream>>>(
            opart0, opart1, lpart, wot + (size_t)l*DM*DM, bo + l*DM, tmpb);
        // xb <- LN(xb + tmpb)   (in-place residual stream, bf16)
        ln_kernel<<<MTOK / 4, 256, 0, stream>>>(xb, tmpb, ln1w + l*DM, ln1b + l*DM, nullptr, xb);
        gemm64_kernel<<<dim3(MTOK / 128, FFP / 64), 256, 0, stream>>>(
            xb, w1t + (size_t)l*FFP*DM, b1 + l*FF, FF, nullptr, ffh, DM, FFP, 2);
        gemm64_kernel<<<dim3(MTOK / 128, DM / 64), 256, 0, stream>>>(
            ffh, w2t + (size_t)l*DM*FFP, b2 + l*DM, DM, nullptr, tmpb, FFP, DM, 1);
        float* outdst = (l == NL - 1) ? outp : nullptr;
        ln_kernel<<<MTOK / 4, 256, 0, stream>>>(xb, tmpb, ln2w + l*DM, ln2b + l*DM, outdst, xb);
    }
}

// Round 15
// 563.569 us; speedup vs baseline: 1.0185x; 1.0050x over previous
//
#include <hip/hip_runtime.h>
#include <hip/hip_bf16.h>
#include <cstdint>

// ---------------------------------------------------------------------------
// ImageEncoder: 4-layer transformer encoder, N=4 S=2048 D=512 H=8 HD=64 F=200.
// bf16 residual stream + bf16 MFMA. FINAL (session best, 566.4us).
// WIN ledger (traffic cuts, 4/4 matched): R13 packed V stores (604.9),
// R16 tmp stream bf16 (580.7), R19 bf16 residual stream (567.7),
// R22 revert-to-best (566.4).
// NEUTRAL/REGRESS ledger (compute-internal, 0/6): R10 2-phase, R14
// counted-vmcnt pipeline (kept, harmless), R15 LDS swizzle (kept), R17 attn
// q-split, R18 LDS-side V-perm, R21 global-side V-perm (all reverted).
// Remaining gap (vs ~110us HBM floor) is kernel-internal in a regime where
// per-kernel counters are occluded by harness fill dispatches; six
// counter-blind structural attempts were neutral-or-negative -> stop.
// ---------------------------------------------------------------------------

typedef __bf16 bf16;
typedef __bf16 bf16x8 __attribute__((ext_vector_type(8)));
typedef __bf16 bf16x4 __attribute__((ext_vector_type(4)));
typedef float f32x4 __attribute__((ext_vector_type(4)));

#define MFMA16(a, b, c) __builtin_amdgcn_mfma_f32_16x16x32_bf16((a), (b), (c), 0, 0, 0)

static constexpr int NB   = 4;
static constexpr int SQ   = 2048;
static constexpr int DM   = 512;
static constexpr int NH   = 8;
static constexpr int HD   = 64;
static constexpr int NL   = 4;
static constexpr int FF   = 200;
static constexpr int FFP  = 256;
static constexpr int MTOK = NB * SQ; // 8192

__device__ __forceinline__ float fast_exp2(float x) {
#if __has_builtin(__builtin_amdgcn_exp2f)
    return __builtin_amdgcn_exp2f(x);
#else
    return exp2f(x);
#endif
}

// async global->LDS, 16 bytes per lane
__device__ __forceinline__ void gld16(bf16* l, const bf16* g) {
    __builtin_amdgcn_global_load_lds(
        (const __attribute__((address_space(1))) void*)g,
        (__attribute__((address_space(3))) void*)l, 16, 0, 0);
}

__device__ __forceinline__ void drain_and_barrier() {
    asm volatile("s_waitcnt vmcnt(0) lgkmcnt(0)" ::: "memory");
    __builtin_amdgcn_s_barrier();
}

// ---------------------------------------------------------------------------
// Weight convert + transpose:  src fp32 [K, Nsrc]  ->  dst bf16 [Npad, Kpad]
// ---------------------------------------------------------------------------
__global__ __launch_bounds__(256) void convw_kernel(
    const float* __restrict__ Wq, const float* __restrict__ Wk,
    const float* __restrict__ Wv, const float* __restrict__ Wo,
    const float* __restrict__ W1, const float* __restrict__ W2,
    bf16* __restrict__ wqkvt, bf16* __restrict__ wot,
    bf16* __restrict__ w1t, bf16* __restrict__ w2t)
{
    __shared__ float tile[32][33];
    const int z = blockIdx.z, l = z / 6, which = z % 6;
    const float* src; bf16* dst; int K, Nsrc, Npad, Kpad;
    switch (which) {
        case 0: src = Wq + (size_t)l*DM*DM; dst = wqkvt + (size_t)(l*3+0)*DM*DM; K=DM; Nsrc=DM; Npad=DM; Kpad=DM; break;
        case 1: src = Wk + (size_t)l*DM*DM; dst = wqkvt + (size_t)(l*3+1)*DM*DM; K=DM; Nsrc=DM; Npad=DM; Kpad=DM; break;
        case 2: src = Wv + (size_t)l*DM*DM; dst = wqkvt + (size_t)(l*3+2)*DM*DM; K=DM; Nsrc=DM; Npad=DM; Kpad=DM; break;
        case 3: src = Wo + (size_t)l*DM*DM; dst = wot   + (size_t)l*DM*DM;       K=DM; Nsrc=DM; Npad=DM; Kpad=DM; break;
        case 4: src = W1 + (size_t)l*DM*FF; dst = w1t   + (size_t)l*FFP*DM;      K=DM; Nsrc=FF; Npad=FFP; Kpad=DM; break;
        default:src = W2 + (size_t)l*FF*DM; dst = w2t   + (size_t)l*DM*FFP;      K=FF; Nsrc=DM; Npad=DM; Kpad=FFP; break;
    }
    const int k0 = blockIdx.x * 32, n0 = blockIdx.y * 32;
    if (k0 >= Kpad || n0 >= Npad) return;
    const int tr = threadIdx.x >> 3, tc = (threadIdx.x & 7) * 4;
    for (int c = 0; c < 4; c++) {
        int sr = k0 + tr, sc = n0 + tc + c;
        tile[tr][tc + c] = (sr < K && sc < Nsrc) ? src[(size_t)sr * Nsrc + sc] : 0.f;
    }
    __syncthreads();
    const int dr = n0 + tr;
    if (dr < Npad) {
        for (int c = 0; c < 4; c++) {
            int dc = k0 + tc + c;
            if (dc < Kpad) dst[(size_t)dr * Kpad + dc] = (bf16)tile[tc + c][tr];
        }
    }
}

// ---------------------------------------------------------------------------
// Positional encoding add + cast (bf16 out only)
// ---------------------------------------------------------------------------
__global__ __launch_bounds__(256) void posenc_kernel(
    const float* __restrict__ f, bf16* __restrict__ xb)
{
    const int t = blockIdx.x * 256 + threadIdx.x;
    const int d2 = t & 255, row = t >> 8, s = row & (SQ - 1);
    const float kfac = -0.03597789207803197f;           // -2*ln(10000)/512
    float dv = __expf((float)d2 * kfac);
    float ang = (float)s * dv;
    float pe0 = sinf(ang), pe1 = cosf(ang);
    const size_t base = (size_t)row * DM + d2 * 2;
    float2 fv = *(const float2*)(f + base);
    float o0 = fv.x + pe0, o1 = fv.y + pe1;
    union { bf16 h[2]; unsigned int u; } pk;
    pk.h[0] = (bf16)o0; pk.h[1] = (bf16)o1;
    *(unsigned int*)(xb + base) = pk.u;
}

// ---------------------------------------------------------------------------
// GEMM core: 128x128 tile, BK=32, 4 waves; 3-buffer counted-vmcnt pipeline +
// XOR chunk-swizzled LDS (2-way max on fragment reads).
// ---------------------------------------------------------------------------
__device__ __forceinline__ void gemm128_core(
    const bf16* __restrict__ A, const bf16* __restrict__ Wt, int K,
    int m0, int n0, bf16* As, bf16* Bs, f32x4 (&acc)[4][4])
{
    const int tid = threadIdx.x;
    const int w = tid >> 6, lane = tid & 63;
    const int l15 = lane & 15, quad = lane >> 4;
    const int srow = w * 16 + (lane >> 2);
    // source pre-swizzle: chunk c of row r lands at physical chunk c^((r>>1)&3)
    const int scol = (((lane & 3) ^ ((lane >> 3) & 3))) * 8;
    const bf16* Ag = A  + (size_t)(m0 + srow) * K + scol;
    const bf16* Bg = Wt + (size_t)(n0 + srow) * K + scol;
    const int wm = (w >> 1) * 64, wn = (w & 1) * 64;

    auto stage = [&](int buf, int k0) {
        bf16* AsW = As + buf * 4096 + w * 512;
        bf16* BsW = Bs + buf * 4096 + w * 512;
        gld16(AsW,        Ag + k0);
        gld16(AsW + 2048, Ag + (size_t)64 * K + k0);
        gld16(BsW,        Bg + k0);
        gld16(BsW + 2048, Bg + (size_t)64 * K + k0);
    };

    const int nsteps = K >> 5;
    stage(0, 0);
    stage(1, 32);

    const int cx = (quad ^ ((l15 >> 1) & 3)) * 8;   // swizzled read chunk
    int buf = 0;
    for (int t = 0; t < nsteps; ++t) {
        if (t + 1 < nsteps)
            asm volatile("s_waitcnt vmcnt(4)" ::: "memory");
        else
            asm volatile("s_waitcnt vmcnt(0)" ::: "memory");
        __builtin_amdgcn_s_barrier();
        if (t + 2 < nsteps) {
            int b2 = buf + 2; if (b2 >= 3) b2 -= 3;
            stage(b2, (t + 2) << 5);
        }
        const bf16* AsR = As + buf * 4096;
        const bf16* BsR = Bs + buf * 4096;
        bf16x8 af[4], bfr[4];
        #pragma unroll
        for (int i = 0; i < 4; i++)
            af[i] = *(const bf16x8*)&AsR[(wm + i * 16 + l15) * 32 + cx];
        #pragma unroll
        for (int j = 0; j < 4; j++)
            bfr[j] = *(const bf16x8*)&BsR[(wn + j * 16 + l15) * 32 + cx];
        #pragma unroll
        for (int i = 0; i < 4; i++)
            #pragma unroll
            for (int j = 0; j < 4; j++)
                acc[i][j] = MFMA16(af[i], bfr[j], acc[i][j]);
        buf = (buf == 2) ? 0 : buf + 1;
    }
}

// 128x64-tile GEMM (wave-tile 64x32), counted-vmcnt + swizzled LDS.
// modes: 0 fp32, 1 bf16, 2 bf16 relu
__global__ __launch_bounds__(256, 4) void gemm64_kernel(
    const bf16* __restrict__ A, const bf16* __restrict__ Wt,
    const float* __restrict__ bias, int nbias,
    float* __restrict__ outf, bf16* __restrict__ outb,
    int K, int Nc, int mode)
{
    __shared__ alignas(16) bf16 As[3 * 128 * 32];
    __shared__ alignas(16) bf16 Bs[3 * 64 * 32];
    const int m0 = blockIdx.x * 128, n0 = blockIdx.y * 64;
    const int tid = threadIdx.x;
    const int w = tid >> 6, lane = tid & 63;
    const int l15 = lane & 15, quad = lane >> 4;
    const int srow = w * 16 + (lane >> 2);
    const int scol = (((lane & 3) ^ ((lane >> 3) & 3))) * 8;
    const bf16* Ag = A  + (size_t)(m0 + srow) * K + scol;
    const bf16* Bg = Wt + (size_t)(n0 + srow) * K + scol;
    const int wm = (w >> 1) * 64, wn = (w & 1) * 32;
    f32x4 acc[4][2] = {};

    auto stage = [&](int buf, int k0) {
        bf16* AsW = As + buf * 4096 + w * 512;
        bf16* BsW = Bs + buf * 2048 + w * 512;
        gld16(AsW,        Ag + k0);
        gld16(AsW + 2048, Ag + (size_t)64 * K + k0);
        gld16(BsW,        Bg + k0);
    };

    const int nsteps = K >> 5;
    stage(0, 0);
    stage(1, 32);

    const int cx = (quad ^ ((l15 >> 1) & 3)) * 8;
    int buf = 0;
    for (int t = 0; t < nsteps; ++t) {
        if (t + 1 < nsteps)
            asm volatile("s_waitcnt vmcnt(3)" ::: "memory");
        else
            asm volatile("s_waitcnt vmcnt(0)" ::: "memory");
        __builtin_amdgcn_s_barrier();
        if (t + 2 < nsteps) {
            int b2 = buf + 2; if (b2 >= 3) b2 -= 3;
            stage(b2, (t + 2) << 5);
        }
        const bf16* AsR = As + buf * 4096;
        const bf16* BsR = Bs + buf * 2048;
        bf16x8 af[4], bfr[2];
        #pragma unroll
        for (int i = 0; i < 4; i++)
            af[i] = *(const bf16x8*)&AsR[(wm + i * 16 + l15) * 32 + cx];
        #pragma unroll
        for (int j = 0; j < 2; j++)
            bfr[j] = *(const bf16x8*)&BsR[(wn + j * 16 + l15) * 32 + cx];
        #pragma unroll
        for (int i = 0; i < 4; i++)
            #pragma unroll
            for (int j = 0; j < 2; j++)
                acc[i][j] = MFMA16(af[i], bfr[j], acc[i][j]);
        buf = (buf == 2) ? 0 : buf + 1;
    }

    #pragma unroll
    for (int j = 0; j < 2; j++) {
        const int col = n0 + wn + j * 16 + l15;
        const float bv = (col < nbias) ? bias[col] : 0.f;
        #pragma unroll
        for (int i = 0; i < 4; i++) {
            const int rbase = m0 + wm + i * 16 + quad * 4;
            #pragma unroll
            for (int r = 0; r < 4; r++) {
                float v = acc[i][j][r] + bv;
                const int row = rbase + r;
                const size_t idx = (size_t)row * Nc + col;
                if (mode == 0)      outf[idx] = v;
                else if (mode == 1) outb[idx] = (bf16)v;
                else                outb[idx] = (bf16)fmaxf(v, 0.f);
            }
        }
    }
}

// Wo GEMM with fused attn-combine: A = bf16((o0+o1)*rl[head]) staged through
// VGPRs. A ds_write address swizzled; B gld16 source swizzled; reads swizzled.
__global__ __launch_bounds__(256, 4) void gemm_wo_kernel(
    const bf16* __restrict__ o0, const bf16* __restrict__ o1,
    const float* __restrict__ lpart,
    const bf16* __restrict__ Wt, const float* __restrict__ bias,
    bf16* __restrict__ outb)
{
    __shared__ alignas(16) bf16 As[2 * 128 * 32];
    __shared__ alignas(16) bf16 Bs[2 * 64 * 32];
    const int m0 = blockIdx.x * 128, n0 = blockIdx.y * 64;
    const int tid = threadIdx.x;
    const int w = tid >> 6, lane = tid & 63;
    const int l15 = lane & 15, quad = lane >> 4;
    const int srow = w * 16 + (lane >> 2);
    const int scol  = (lane & 3) * 8;                                  // linear (A reg loads)
    const int scolz = (((lane & 3) ^ ((lane >> 3) & 3))) * 8;          // swizzled (B gld16 src)
    const int row0 = m0 + srow, row1 = row0 + 64;
    const bf16* Bg = Wt + (size_t)(n0 + srow) * DM + scolz;
    const int wm = (w >> 1) * 64, wn = (w & 1) * 32;

    // per-head reciprocal softmax denominators for this thread's two A rows
    const int b0 = (((row0 >> 11) * 8) << 11) | (row0 & (SQ - 1));
    const int b1 = (((row1 >> 11) * 8) << 11) | (row1 & (SQ - 1));
    float rl0[8], rl1[8];
    #pragma unroll
    for (int h = 0; h < 8; h++) {
        rl0[h] = 1.f / (lpart[b0 + (h << 11)] + lpart[65536 + b0 + (h << 11)]);
        rl1[h] = 1.f / (lpart[b1 + (h << 11)] + lpart[65536 + b1 + (h << 11)]);
    }

    const bf16* A0g  = o0 + (size_t)row0 * DM + scol;
    const bf16* A0g2 = o0 + (size_t)row1 * DM + scol;
    const bf16* A1g  = o1 + (size_t)row0 * DM + scol;
    const bf16* A1g2 = o1 + (size_t)row1 * DM + scol;
    f32x4 acc[4][2] = {};

    // swizzled ds_write position: row (lane>>2), physical chunk (lane&3)^((lane>>3)&3)
    const int adst = (lane >> 2) * 32 + scolz;

    auto combineStore = [&](int buf, int h, bf16x8 a0, bf16x8 c0, bf16x8 a1, bf16x8 c1) {
        bf16x8 s0, s1;
        #pragma unroll
        for (int i = 0; i < 8; i++) {
            s0[i] = (bf16)(((float)a0[i] + (float)c0[i]) * rl0[h]);
            s1[i] = (bf16)(((float)a1[i] + (float)c1[i]) * rl1[h]);
        }
        bf16* d = As + buf * 4096 + w * 512 + adst;
        *(bf16x8*)d          = s0;
        *(bf16x8*)(d + 2048) = s1;
    };

    { // prologue: step 0
        bf16x8 a0 = *(const bf16x8*)(A0g);
        bf16x8 c0 = *(const bf16x8*)(A1g);
        bf16x8 a1 = *(const bf16x8*)(A0g2);
        bf16x8 c1 = *(const bf16x8*)(A1g2);
        gld16(Bs + w * 512, Bg);
        combineStore(0, 0, a0, c0, a1, c1);
        drain_and_barrier();
    }

    const int cx = (quad ^ ((l15 >> 1) & 3)) * 8;
    int buf = 0;
    for (int t = 0; t < 16; ++t) {
        const bool pre = (t + 1 < 16);
        bf16x8 na0, nc0, na1, nc1;
        if (pre) {
            const int k1 = (t + 1) * 32;
            na0 = *(const bf16x8*)(A0g  + k1);
            nc0 = *(const bf16x8*)(A1g  + k1);
            na1 = *(const bf16x8*)(A0g2 + k1);
            nc1 = *(const bf16x8*)(A1g2 + k1);
            gld16(Bs + (buf ^ 1) * 2048 + w * 512, Bg + k1);
        }

        const bf16* AsR = As + buf * 4096;
        const bf16* BsR = Bs + buf * 2048;
        bf16x8 af[4], bfr[2];
        #pragma unroll
        for (int i = 0; i < 4; i++)
            af[i] = *(const bf16x8*)&AsR[(wm + i * 16 + l15) * 32 + cx];
        #pragma unroll
        for (int j = 0; j < 2; j++)
            bfr[j] = *(const bf16x8*)&BsR[(wn + j * 16 + l15) * 32 + cx];
        #pragma unroll
        for (int i = 0; i < 4; i++)
            #pragma unroll
            for (int j = 0; j < 2; j++)
                acc[i][j] = MFMA16(af[i], bfr[j], acc[i][j]);

        if (pre) combineStore(buf ^ 1, (t + 1) >> 1, na0, nc0, na1, nc1);
        drain_and_barrier();
        buf ^= 1;
    }

    #pragma unroll
    for (int j = 0; j < 2; j++) {
        const int col = n0 + wn + j * 16 + l15;
        const float bv = bias[col];
        #pragma unroll
        for (int i = 0; i < 4; i++) {
            const int rbase = m0 + wm + i * 16 + quad * 4;
            #pragma unroll
            for (int r = 0; r < 4; r++)
                outb[(size_t)(rbase + r) * DM + col] = (bf16)(acc[i][j][r] + bv);
        }
    }
}

// fused QKV (128x128 core). Q gets (1/sqrt(HD))*log2(e) folded in;
// V written transposed to [n,h,hd,s] with packed 8B stores (R13).
__global__ __launch_bounds__(256, 3) void gemm128_qkv_kernel(
    const bf16* __restrict__ xb, const bf16* __restrict__ Wt,
    const float* __restrict__ bq, const float* __restrict__ bk,
    const float* __restrict__ bv,
    bf16* __restrict__ qb, bf16* __restrict__ kb, bf16* __restrict__ vtb)
{
    __shared__ alignas(16) bf16 As[3 * 128 * 32];
    __shared__ alignas(16) bf16 Bs[3 * 128 * 32];
    const int m0 = blockIdx.x * 128, n0 = blockIdx.y * 128;
    f32x4 acc[4][4] = {};
    gemm128_core(xb, Wt, DM, m0, n0, As, Bs, acc);

    const int lane = threadIdx.x & 63;
    const int l15 = lane & 15, quad = lane >> 4;
    const int w = threadIdx.x >> 6;
    const int wm = (w >> 1) * 64, wn = (w & 1) * 64;
    const int which = n0 >> 9;
    const float* bias = (which == 0) ? bq : (which == 1) ? bk : bv;
    // 0.125 = 1/sqrt(64); *1.44269504 so attn can use exp2 directly
    const float scale = (which == 0) ? 0.18033688f : 1.f;
    #pragma unroll
    for (int j = 0; j < 4; j++) {
        const int c = (n0 & 511) + wn + j * 16 + l15;
        const float bvv = bias[c];
        #pragma unroll
        for (int i = 0; i < 4; i++) {
            const int rbase = m0 + wm + i * 16 + quad * 4;
            if (which == 2) {
                // V: r=0..3 are s-contiguous in vtb -> one packed 8B store
                union { bf16 h[4]; uint2 u2; } pk;
                #pragma unroll
                for (int r = 0; r < 4; r++)
                    pk.h[r] = (bf16)(acc[i][j][r] + bvv);
                const int n = rbase >> 11, s = rbase & (SQ - 1);
                const int h = c >> 6, hd = c & 63;
                *(uint2*)&vtb[((size_t)(((n << 3) | h) << 6 | hd) << 11) | s] = pk.u2;
            } else {
                #pragma unroll
                for (int r = 0; r < 4; r++) {
                    float v = (acc[i][j][r] + bvv) * scale;
                    const int row = rbase + r;
                    if (which == 0) qb[(size_t)row * DM + c] = (bf16)v;
                    else            kb[(size_t)row * DM + c] = (bf16)v;
                }
            }
        }
    }
}

// ---------------------------------------------------------------------------
// Flash attention. Block: one (n,h,kvhalf), 256 q (4 waves x 64 q),
// 16 kv-tiles of 64. Grid 512.
// S^T = K·Q^T (16x16x32): lane holds q=l15, kv=quad*4+r; kv-permuted K=32 PV;
// lsum = P*ones via MFMA. Unnormalized O + lsum partials out.
// ---------------------------------------------------------------------------
__global__ __launch_bounds__(256, 2) void attn_kernel(
    const bf16* __restrict__ qb, const bf16* __restrict__ kb,
    const bf16* __restrict__ vtb,
    bf16* __restrict__ opart0, bf16* __restrict__ opart1,
    float* __restrict__ lpart)
{
    __shared__ alignas(16) bf16 Kt[2][64][72];
    __shared__ alignas(16) bf16 Vt[2 * 64 * 68];
    const int tid = threadIdx.x;
    const int w = tid >> 6, lane = tid & 63;
    const int l15 = lane & 15, quad = lane >> 4;
    const int id = blockIdx.x;          // id&7 fixed per (nh,kvhalf) -> XCD
    const int kvhalf = id & 1;
    const int nh = (id >> 1) & 31;
    const int qblk = id >> 6;           // [0,8)
    const int n = nh >> 3, h = nh & 7;
    const int q0 = qblk * 256 + w * 64;
    const int kvbase = kvhalf * (SQ / 2);
    const bf16* qbase = qb + (size_t)n * SQ * DM + h * HD;
    const bf16* kbase = kb + (size_t)n * SQ * DM + h * HD;
    const bf16* vbase = vtb + (size_t)nh * HD * SQ;

    // Q fragments (B-operand of S^T: n=q=l15, k=d=quad*8+j), 4 mi tiles
    bf16x8 qf[4][2];
    #pragma unroll
    for (int mi = 0; mi < 4; mi++)
        #pragma unroll
        for (int hh = 0; hh < 2; hh++)
            qf[mi][hh] = *(const bf16x8*)(qbase + (size_t)(q0 + mi*16 + l15) * DM + hh*32 + quad*8);

    bf16x8 ones8;
    #pragma unroll
    for (int i = 0; i < 8; i++) ones8[i] = (bf16)1.0f;

    f32x4 o[4][4] = {};
    f32x4 lacc[4] = {};

    // staging: thread covers (srow, seg..seg+16) of the 64x64 tile
    const int srow = tid >> 2, seg = (tid & 3) * 16;
    const bf16* krow = kbase + (size_t)(kvbase + srow) * DM + seg;  // K rows = kv
    const bf16* vrow = vbase + (size_t)srow * SQ + kvbase + seg;    // V rows = hd

    auto storeV = [&](int buf, bf16x8 a, bf16x8 b) {
        bf16* d = &Vt[(buf * 64 + srow) * 68 + seg];
        bf16x4 p0, p1, p2, p3;
        #pragma unroll
        for (int i = 0; i < 4; i++) { p0[i]=a[i]; p1[i]=a[i+4]; p2[i]=b[i]; p3[i]=b[i+4]; }
        *(bf16x4*)(d)      = p0;
        *(bf16x4*)(d + 4)  = p1;
        *(bf16x4*)(d + 8)  = p2;
        *(bf16x4*)(d + 12) = p3;
    };

    { // prologue: stage tile 0 of this half
        bf16x8 k0 = *(const bf16x8*)(krow);
        bf16x8 k1 = *(const bf16x8*)(krow + 8);
        bf16x8 v0 = *(const bf16x8*)(vrow);
        bf16x8 v1 = *(const bf16x8*)(vrow + 8);
        *(bf16x8*)&Kt[0][srow][seg]     = k0;
        *(bf16x8*)&Kt[0][srow][seg + 8] = k1;
        storeV(0, v0, v1);
    }

    const int NT = SQ / 128;   // 16 tiles per half
    for (int jt = 0; jt < NT; jt++) {
        const int buf = jt & 1;
        __syncthreads();   // buf writes visible; prev iter's reads complete
        const bool pre = (jt + 1 < NT);
        bf16x8 k0, k1, v0, v1;
        if (pre) {         // next tile's global loads issued early
            const bf16* kp = krow + (size_t)(jt + 1) * 64 * DM;
            const bf16* vp = vrow + (jt + 1) * 64;
            k0 = *(const bf16x8*)(kp);
            k1 = *(const bf16x8*)(kp + 8);
            v0 = *(const bf16x8*)(vp);
            v1 = *(const bf16x8*)(vp + 8);
        }

        #pragma unroll
        for (int sp = 0; sp < 2; sp++) {
            // two 16-row kv chunks of this 32-span
            bf16x8 kfA0 = *(const bf16x8*)&Kt[buf][sp*32 + l15][quad*8];
            bf16x8 kfA1 = *(const bf16x8*)&Kt[buf][sp*32 + l15][32 + quad*8];
            bf16x8 kfB0 = *(const bf16x8*)&Kt[buf][sp*32 + 16 + l15][quad*8];
            bf16x8 kfB1 = *(const bf16x8*)&Kt[buf][sp*32 + 16 + l15][32 + quad*8];
            bf16x8 pf[4];
            #pragma unroll
            for (int mi = 0; mi < 4; mi++) {
                f32x4 sa = {}, sb = {};
                sa = MFMA16(kfA0, qf[mi][0], sa);
                sa = MFMA16(kfA1, qf[mi][1], sa);
                sb = MFMA16(kfB0, qf[mi][0], sb);
                sb = MFMA16(kfB1, qf[mi][1], sb);
                bf16x8 p;
                #pragma unroll
                for (int r = 0; r < 4; r++) {
                    p[r]     = (bf16)fast_exp2(sa[r]);
                    p[r + 4] = (bf16)fast_exp2(sb[r]);
                }
                pf[mi] = p;                      // permuted K=32 A-frag
                lacc[mi] = MFMA16(p, ones8, lacc[mi]);   // row sums
            }
            // O[q][hd] += P V  (K=32, kv-permuted; V rows follow pi)
            #pragma unroll
            for (int d4 = 0; d4 < 4; d4++) {
                const bf16* vp2 = &Vt[(buf*64 + d4*16 + l15) * 68 + sp*32 + quad*4];
                bf16x4 vlo = *(const bf16x4*)(vp2);
                bf16x4 vhi = *(const bf16x4*)(vp2 + 16);
                bf16x8 vf;
                #pragma unroll
                for (int i = 0; i < 4; i++) { vf[i] = vlo[i]; vf[i+4] = vhi[i]; }
                #pragma unroll
                for (int mi = 0; mi < 4; mi++)
                    o[mi][d4] = MFMA16(pf[mi], vf, o[mi][d4]);
            }
        }

        if (pre) {
            *(bf16x8*)&Kt[buf^1][srow][seg]     = k0;
            *(bf16x8*)&Kt[buf^1][srow][seg + 8] = k1;
            storeV(buf^1, v0, v1);
        }
    }

    // lacc[mi][r] = lsum for q = q0 + mi*16 + quad*4 + r (same in every l15
    // lane). One lane per quad writes 4 contiguous floats.
    if (l15 == 0) {
        const int base = (kvhalf << 16) + (nh << 11) + q0 + quad * 4;
        #pragma unroll
        for (int mi = 0; mi < 4; mi++) {
            float4 v4 = make_float4(lacc[mi][0], lacc[mi][1], lacc[mi][2], lacc[mi][3]);
            *(float4*)&lpart[base + mi * 16] = v4;
        }
    }

    // write unnormalized O partial (bf16)
    bf16* op = kvhalf ? opart1 : opart0;
    #pragma unroll
    for (int mi = 0; mi < 4; mi++) {
        #pragma unroll
        for (int d4 = 0; d4 < 4; d4++) {
            const int col = h * HD + d4 * 16 + l15;
            #pragma unroll
            for (int r = 0; r < 4; r++) {
                const int row = n * SQ + q0 + mi*16 + quad*4 + r;
                op[(size_t)row * DM + col] = (bf16)o[mi][d4][r];
            }
        }
    }
}

// ---------------------------------------------------------------------------
// Residual + LayerNorm: out = LN(res + add) * g + beta with bf16 res and
// add streams. Stats in fp32. Writes bf16 xb; optional fp32 out (final layer).
// ---------------------------------------------------------------------------
__global__ __launch_bounds__(256) void ln_kernel(
    const bf16* __restrict__ res, const bf16* __restrict__ add,
    const float* __restrict__ g, const float* __restrict__ beta,
    float* __restrict__ outf, bf16* __restrict__ outb)
{
    const int w = threadIdx.x >> 6, lane = threadIdx.x & 63;
    const size_t row = (size_t)blockIdx.x * 4 + w;
    const bf16* rp = res + row * DM;
    const bf16* ap = add + row * DM;
    float4 v[2];
    float s = 0.f, s2 = 0.f;
    #pragma unroll
    for (int i = 0; i < 2; i++) {
        const int idx = i * 64 + lane;
        bf16x4 a4 = *(const bf16x4*)(rp + idx * 4);
        bf16x4 c4 = *(const bf16x4*)(ap + idx * 4);
        float x0 = (float)a4[0] + (float)c4[0], x1 = (float)a4[1] + (float)c4[1];
        float x2 = (float)a4[2] + (float)c4[2], x3 = (float)a4[3] + (float)c4[3];
        v[i] = make_float4(x0, x1, x2, x3);
        s  += x0 + x1 + x2 + x3;
        s2 += x0*x0 + x1*x1 + x2*x2 + x3*x3;
    }
    for (int m = 1; m < 64; m <<= 1) {
        s  += __shfl_xor(s,  m, 64);
        s2 += __shfl_xor(s2, m, 64);
    }
    const float mean = s * (1.f / DM);
    const float var  = s2 * (1.f / DM) - mean * mean;
    const float rstd = rsqrtf(var + 1e-5f);
    #pragma unroll
    for (int i = 0; i < 2; i++) {
        const int idx = i * 64 + lane;
        float4 gw = ((const float4*)g)[idx], bw = ((const float4*)beta)[idx];
        float o0 = (v[i].x - mean) * rstd * gw.x + bw.x;
        float o1 = (v[i].y - mean) * rstd * gw.y + bw.y;
        float o2 = (v[i].z - mean) * rstd * gw.z + bw.z;
        float o3 = (v[i].w - mean) * rstd * gw.w + bw.w;
        union { bf16 h[4]; uint2 u; } pk;
        pk.h[0] = (bf16)o0; pk.h[1] = (bf16)o1; pk.h[2] = (bf16)o2; pk.h[3] = (bf16)o3;
        *(uint2*)(outb + row * DM + idx * 4) = pk.u;
        if (outf)
            ((float4*)(outf + row * DM))[idx] = make_float4(o0, o1, o2, o3);
    }
}

// ---------------------------------------------------------------------------
extern "C" void kernel_launch(void* const* d_in, const int* in_sizes, int n_in,
                              void* d_out, int out_size, void* d_ws, size_t ws_size,
                              hipStream_t stream)
{
    const float* features = (const float*)d_in[0];
    const float* Wq  = (const float*)d_in[1];
    const float* bq  = (const float*)d_in[2];
    const float* Wk  = (const float*)d_in[3];
    const float* bk  = (const float*)d_in[4];
    const float* Wv  = (const float*)d_in[5];
    const float* bv  = (const float*)d_in[6];
    const float* Wo  = (const float*)d_in[7];
    const float* bo  = (const float*)d_in[8];
    const float* W1  = (const float*)d_in[9];
    const float* b1  = (const float*)d_in[10];
    const float* W2  = (const float*)d_in[11];
    const float* b2  = (const float*)d_in[12];
    const float* ln1w = (const float*)d_in[13];
    const float* ln1b = (const float*)d_in[14];
    const float* ln2w = (const float*)d_in[15];
    const float* ln2b = (const float*)d_in[16];
    float* outp = (float*)d_out;

    char* p = (char*)d_ws;
    size_t off = 0;
    auto alloc = [&](size_t bytes) { void* r = p + off; off = (off + bytes + 255) & ~(size_t)255; return r; };
    const size_t tokD = (size_t)MTOK * DM;
    bf16* tmpb   = (bf16*)alloc(tokD * 2);
    bf16* xb     = (bf16*)alloc(tokD * 2);
    bf16* qb     = (bf16*)alloc(tokD * 2);
    bf16* kb     = (bf16*)alloc(tokD * 2);
    bf16* vtb    = (bf16*)alloc(tokD * 2);
    bf16* opart0 = (bf16*)alloc(tokD * 2);
    bf16* opart1 = (bf16*)alloc(tokD * 2);
    float* lpart = (float*)alloc(2 * 65536 * 4);
    bf16* ffh    = (bf16*)alloc((size_t)MTOK * FFP * 2);
    bf16* wqkvt  = (bf16*)alloc((size_t)NL * 3 * DM * DM * 2);
    bf16* wot    = (bf16*)alloc((size_t)NL * DM * DM * 2);
    bf16* w1t    = (bf16*)alloc((size_t)NL * FFP * DM * 2);
    bf16* w2t    = (bf16*)alloc((size_t)NL * DM * FFP * 2);
    (void)ws_size; (void)in_sizes; (void)n_in; (void)out_size;

    convw_kernel<<<dim3(16, 16, NL * 6), 256, 0, stream>>>(
        Wq, Wk, Wv, Wo, W1, W2, wqkvt, wot, w1t, w2t);

    posenc_kernel<<<MTOK, 256, 0, stream>>>(features, xb);

    for (int l = 0; l < NL; l++) {
        const bf16* wqkvt_l = wqkvt + (size_t)l * 3 * DM * DM;
        gemm128_qkv_kernel<<<dim3(MTOK / 128, 1536 / 128), 256, 0, stream>>>(
            xb, wqkvt_l, bq + l*DM, bk + l*DM, bv + l*DM, qb, kb, vtb);
        attn_kernel<<<512, 256, 0, stream>>>(qb, kb, vtb, opart0, opart1, lpart);
        // tmpb = combine(o0,o1,lpart) @ Wo + bo   (combine fused into staging)
        gemm_wo_kernel<<<dim3(MTOK / 128, DM / 64), 256, 0, stream>>>(
            opart0, opart1, lpart, wot + (size_t)l*DM*DM, bo + l*DM, tmpb);
        // xb <- LN(xb + tmpb)   (in-place residual stream, bf16)
        ln_kernel<<<MTOK / 4, 256, 0, stream>>>(xb, tmpb, ln1w + l*DM, ln1b + l*DM, nullptr, xb);
        gemm64_kernel<<<dim3(MTOK / 128, FFP / 64), 256, 0, stream>>>(
            xb, w1t + (size_t)l*FFP*DM, b1 + l*FF, FF, nullptr, ffh, DM, FFP, 2);
        gemm64_kernel<<<dim3(MTOK / 128, DM / 64), 256, 0, stream>>>(
            ffh, w2t + (size_t)l*DM*FFP, b2 + l*DM, DM, nullptr, tmpb, FFP, DM, 1);
        float* outdst = (l == NL - 1) ? outp : nullptr;
        ln_kernel<<<MTOK / 4, 256, 0, stream>>>(xb, tmpb, ln2w + l*DM, ln2b + l*DM, outdst, xb);
    }
}